// Round 3
// baseline (454.221 us; speedup 1.0000x reference)
//
#include <hip/hip_runtime.h>
#include <hip/hip_bf16.h>

#define N_NODES 50000
#define N_EDGES 600000
#define N_PAIRS 100000

typedef __attribute__((ext_vector_type(8))) short bf16x8;
typedef __attribute__((ext_vector_type(4))) float f32x4;

__device__ inline unsigned short f2b(float f) {
    unsigned u = __float_as_uint(f);
    unsigned r = u + 0x7fff + ((u >> 16) & 1);
    return (unsigned short)(r >> 16);
}
__device__ inline float b2f(unsigned short h) {
    return __uint_as_float(((unsigned)h) << 16);
}

// ---- convert x (fp32 [N][128]) into A1[:, 0:128] bf16 (ld 256) ----
__global__ void k_convert_x(const float* __restrict__ x, unsigned short* __restrict__ A1) {
    int idx = blockIdx.x * blockDim.x + threadIdx.x;
    if (idx >= N_NODES * 32) return;
    int row = idx >> 5, c4 = (idx & 31) * 4;
    float4 v = *(const float4*)(x + row * 128 + c4);
    unsigned lo = (unsigned)f2b(v.x) | ((unsigned)f2b(v.y) << 16);
    unsigned hi = (unsigned)f2b(v.z) | ((unsigned)f2b(v.w) << 16);
    uint2 o; o.x = lo; o.y = hi;
    *(uint2*)(A1 + row * 256 + c4) = o;
}

// ---- build transposed bf16 weights ----
__global__ void k_prep_w(const float* __restrict__ Ws1, const float* __restrict__ Wn1,
                         const float* __restrict__ Ws2, const float* __restrict__ Wn2,
                         const float* __restrict__ Wd1, const float* __restrict__ Wd2,
                         unsigned short* __restrict__ WT1, unsigned short* __restrict__ WT2,
                         unsigned short* __restrict__ WdT1, unsigned short* __restrict__ WdT2) {
    int id = blockIdx.x * blockDim.x + threadIdx.x;
    if (id < 32768) {
        int k = id & 255, n = id >> 8;
        float v = (k < 128) ? Ws1[k * 128 + n] : Wn1[(k - 128) * 128 + n];
        WT1[n * 256 + k] = f2b(v);
    } else if (id < 65536) {
        int r = id - 32768; int k = r & 255, n = r >> 8;
        float v = (k < 128) ? Ws2[k * 128 + n] : Wn2[(k - 128) * 128 + n];
        WT2[n * 256 + k] = f2b(v);
    } else if (id < 81920) {
        int r = id - 65536; int k = r & 127, n = r >> 7;
        WdT1[n * 128 + k] = f2b(Wd1[k * 128 + n]);
    } else if (id < 98304) {
        int r = id - 81920; int k = r & 127, n = r >> 7;
        WdT2[n * 128 + k] = f2b(Wd2[k * 128 + n]);
    }
}

// ---- CSR build ----
__global__ void k_deg(const int* __restrict__ dst, int* __restrict__ deg) {
    int e = blockIdx.x * blockDim.x + threadIdx.x;
    if (e < N_EDGES) atomicAdd(&deg[dst[e]], 1);
}

__global__ void k_scan1(const int* __restrict__ deg, int* __restrict__ row_ptr,
                        int* __restrict__ bsum, int n) {
    __shared__ int tmp[1024];
    int i = blockIdx.x * 1024 + threadIdx.x;
    int d = (i < n) ? deg[i] : 0;
    tmp[threadIdx.x] = d;
    __syncthreads();
    int run = d;
    for (int off = 1; off < 1024; off <<= 1) {
        int t = (threadIdx.x >= off) ? tmp[threadIdx.x - off] : 0;
        __syncthreads();
        run += t;
        tmp[threadIdx.x] = run;
        __syncthreads();
    }
    if (i < n) row_ptr[i] = run - d;
    if (threadIdx.x == 1023) bsum[blockIdx.x] = run;
}

__global__ void k_scan2(int* __restrict__ bsum, int nb) {
    if (blockIdx.x == 0 && threadIdx.x == 0) {
        int acc = 0;
        for (int b = 0; b < nb; b++) { int t = bsum[b]; bsum[b] = acc; acc += t; }
    }
}

__global__ void k_add(int* __restrict__ row_ptr, int* __restrict__ cursor,
                      const int* __restrict__ bsum, int n) {
    int i = blockIdx.x * 1024 + threadIdx.x;
    if (i < n) {
        int v = row_ptr[i] + bsum[blockIdx.x];
        row_ptr[i] = v;
        cursor[i] = v;
    }
    if (i == 0) row_ptr[n] = N_EDGES;
}

__global__ void k_scatter(const int* __restrict__ src, const int* __restrict__ dst,
                          int* __restrict__ cursor, int* __restrict__ colA) {
    int e = blockIdx.x * blockDim.x + threadIdx.x;
    if (e < N_EDGES) {
        int d = dst[e];
        int slot = atomicAdd(&cursor[d], 1);
        colA[slot] = src[e];
    }
}

// ---- mean aggregation (R1 proven version): one wave per dst node, lane = 2 feats ----
template <bool BF16IN>
__global__ __launch_bounds__(256) void k_agg(const float* __restrict__ xf,
                                             const unsigned short* __restrict__ hb, int ldh,
                                             const int* __restrict__ row_ptr,
                                             const int* __restrict__ colA,
                                             unsigned short* __restrict__ outm, int ldo) {
    int w = (blockIdx.x * blockDim.x + threadIdx.x) >> 6;
    int lane = threadIdx.x & 63;
    if (w >= N_NODES) return;
    int s = row_ptr[w], e = row_ptr[w + 1];
    float a0 = 0.f, a1 = 0.f;
    for (int base = s; base < e; base += 64) {
        int ce = (base + lane < e) ? colA[base + lane] : 0;
        int cnt = min(64, e - base);
        int i = 0;
        for (; i + 1 < cnt; i += 2) {
            int s0 = __shfl(ce, i, 64);
            int s1 = __shfl(ce, i + 1, 64);
            if (BF16IN) {
                unsigned v0 = *(const unsigned*)(hb + s0 * ldh + 2 * lane);
                unsigned v1 = *(const unsigned*)(hb + s1 * ldh + 2 * lane);
                a0 += b2f(v0 & 0xffff) + b2f(v1 & 0xffff);
                a1 += b2f(v0 >> 16) + b2f(v1 >> 16);
            } else {
                float2 v0 = *(const float2*)(xf + s0 * 128 + 2 * lane);
                float2 v1 = *(const float2*)(xf + s1 * 128 + 2 * lane);
                a0 += v0.x + v1.x;
                a1 += v0.y + v1.y;
            }
        }
        if (i < cnt) {
            int s0 = __shfl(ce, i, 64);
            if (BF16IN) {
                unsigned v0 = *(const unsigned*)(hb + s0 * ldh + 2 * lane);
                a0 += b2f(v0 & 0xffff);
                a1 += b2f(v0 >> 16);
            } else {
                float2 v0 = *(const float2*)(xf + s0 * 128 + 2 * lane);
                a0 += v0.x;
                a1 += v0.y;
            }
        }
    }
    float rd = 1.0f / (float)max(e - s, 1);
    unsigned o = (unsigned)f2b(a0 * rd) | ((unsigned)f2b(a1 * rd) << 16);
    *(unsigned*)(outm + w * ldo + 2 * lane) = o;
}

// ---- SAGE layer GEMM: H = act(A[M,K] @ BT^T + b) ----
__global__ __launch_bounds__(256) void k_gemm(const unsigned short* __restrict__ A, int lda, int K,
                                              const unsigned short* __restrict__ BT,
                                              const float* __restrict__ bias,
                                              unsigned short* __restrict__ Hout, int ldo,
                                              int M, int relu) {
    int wv = threadIdx.x >> 6, lane = threadIdx.x & 63;
    int lr = lane & 15, lq = lane >> 4;
    int r0 = blockIdx.x * 64 + wv * 16;
    int arow = r0 + lr;
    if (arow > M - 1) arow = M - 1;
    f32x4 acc[8];
    f32x4 zero = {0.f, 0.f, 0.f, 0.f};
#pragma unroll
    for (int ct = 0; ct < 8; ct++) acc[ct] = zero;
    for (int kb = 0; kb < K; kb += 32) {
        int ka = kb + lq * 8;
        bf16x8 af = *(const bf16x8*)(A + (size_t)arow * lda + ka);
#pragma unroll
        for (int ct = 0; ct < 8; ct++) {
            bf16x8 bf = *(const bf16x8*)(BT + (ct * 16 + lr) * K + ka);
            acc[ct] = __builtin_amdgcn_mfma_f32_16x16x32_bf16(af, bf, acc[ct], 0, 0, 0);
        }
    }
#pragma unroll
    for (int ct = 0; ct < 8; ct++) {
        int colc = ct * 16 + lr;
        float bv = bias[colc];
#pragma unroll
        for (int r = 0; r < 4; r++) {
            int row = r0 + lq * 4 + r;
            if (row < M) {
                float v = acc[ct][r] + bv;
                if (relu) v = fmaxf(v, 0.f);
                Hout[(size_t)row * ldo + colc] = f2b(v);
            }
        }
    }
}

// ---- z gather: z[p] = h2b[src[p]] * h2b[dst[p]] (bf16), pos then neg ----
__global__ __launch_bounds__(256) void k_zgather(const unsigned short* __restrict__ h2b,
                                                 const int* __restrict__ pos_src,
                                                 const int* __restrict__ pos_dst,
                                                 const int* __restrict__ neg_src,
                                                 const int* __restrict__ neg_dst,
                                                 unsigned short* __restrict__ z) {
    int idx = blockIdx.x * 256 + threadIdx.x;    // 200000*16 threads, 16B each
    int p = idx >> 4, c = idx & 15;
    int s, d;
    if (p < N_PAIRS) { s = pos_src[p]; d = pos_dst[p]; }
    else { s = neg_src[p - N_PAIRS]; d = neg_dst[p - N_PAIRS]; }
    uint4 av = *(const uint4*)(h2b + (size_t)s * 128 + c * 8);
    uint4 bv = *(const uint4*)(h2b + (size_t)d * 128 + c * 8);
    uint4 res;
    unsigned* rp = (unsigned*)&res;
    const unsigned* ap = (const unsigned*)&av;
    const unsigned* bp = (const unsigned*)&bv;
#pragma unroll
    for (int j = 0; j < 4; j++) {
        unsigned short lo = f2b(b2f(ap[j] & 0xffff) * b2f(bp[j] & 0xffff));
        unsigned short hi = f2b(b2f(ap[j] >> 16) * b2f(bp[j] >> 16));
        rp[j] = (unsigned)lo | ((unsigned)hi << 16);
    }
    *(uint4*)(z + (size_t)p * 128 + c * 8) = res;
}

// ---- decoder MLP over contiguous z: per-wave 16-row tile, 2 layers + dot ----
__global__ __launch_bounds__(256) void k_mlp(const unsigned short* __restrict__ z,
                                             const unsigned short* __restrict__ WdT1,
                                             const unsigned short* __restrict__ WdT2,
                                             const float* __restrict__ bd1,
                                             const float* __restrict__ bd2,
                                             const float* __restrict__ Wd3,
                                             const float* __restrict__ bd3,
                                             float* __restrict__ out) {
    __shared__ unsigned short t1[4][16][136];
    const int tid = threadIdx.x;
    const int wv = tid >> 6, lane = tid & 63, lr = lane & 15, lq = lane >> 4;
    const int row0 = blockIdx.x * 64 + wv * 16;
    const unsigned short* zr = z + (size_t)(row0 + lr) * 128;
    f32x4 zero = {0.f, 0.f, 0.f, 0.f};
    f32x4 acc[8];
#pragma unroll
    for (int ct = 0; ct < 8; ct++) acc[ct] = zero;
#pragma unroll
    for (int kb = 0; kb < 4; kb++) {
        bf16x8 af = *(const bf16x8*)(zr + kb * 32 + lq * 8);
#pragma unroll
        for (int ct = 0; ct < 8; ct++) {
            bf16x8 bf = *(const bf16x8*)(WdT1 + (ct * 16 + lr) * 128 + kb * 32 + lq * 8);
            acc[ct] = __builtin_amdgcn_mfma_f32_16x16x32_bf16(af, bf, acc[ct], 0, 0, 0);
        }
    }
#pragma unroll
    for (int ct = 0; ct < 8; ct++) {
        int colc = ct * 16 + lr;
        float bv = bd1[colc];
#pragma unroll
        for (int r = 0; r < 4; r++) {
            float v = fmaxf(acc[ct][r] + bv, 0.f);
            t1[wv][lq * 4 + r][colc] = f2b(v);
        }
    }
    __syncthreads();
#pragma unroll
    for (int ct = 0; ct < 8; ct++) acc[ct] = zero;
#pragma unroll
    for (int kb = 0; kb < 4; kb++) {
        bf16x8 af = *(const bf16x8*)(&t1[wv][lr][kb * 32 + lq * 8]);
#pragma unroll
        for (int ct = 0; ct < 8; ct++) {
            bf16x8 bf = *(const bf16x8*)(WdT2 + (ct * 16 + lr) * 128 + kb * 32 + lq * 8);
            acc[ct] = __builtin_amdgcn_mfma_f32_16x16x32_bf16(af, bf, acc[ct], 0, 0, 0);
        }
    }
    float sc[4] = {0.f, 0.f, 0.f, 0.f};
#pragma unroll
    for (int ct = 0; ct < 8; ct++) {
        int colc = ct * 16 + lr;
        float bv = bd2[colc];
        float w3 = Wd3[colc];
#pragma unroll
        for (int r = 0; r < 4; r++) {
            float v = fmaxf(acc[ct][r] + bv, 0.f);
            sc[r] += v * w3;
        }
    }
#pragma unroll
    for (int m = 1; m < 16; m <<= 1) {
#pragma unroll
        for (int r = 0; r < 4; r++) sc[r] += __shfl_xor(sc[r], m, 64);
    }
    if (lr == 0) {
        float b3 = bd3[0];
#pragma unroll
        for (int r = 0; r < 4; r++) {
            out[row0 + lq * 4 + r] = sc[r] + b3;
        }
    }
}

static inline size_t alignup(size_t v) { return (v + 255) & ~(size_t)255; }

extern "C" void kernel_launch(void* const* d_in, const int* in_sizes, int n_in,
                              void* d_out, int out_size, void* d_ws, size_t ws_size,
                              hipStream_t stream) {
    const float* x = (const float*)d_in[0];
    const int* edge_src = (const int*)d_in[1];
    const int* edge_dst = (const int*)d_in[2];
    const int* pos_src = (const int*)d_in[3];
    const int* pos_dst = (const int*)d_in[4];
    const int* neg_src = (const int*)d_in[5];
    const int* neg_dst = (const int*)d_in[6];
    const float* Ws1 = (const float*)d_in[7];
    const float* Wn1 = (const float*)d_in[8];
    const float* b1 = (const float*)d_in[9];
    const float* Ws2 = (const float*)d_in[10];
    const float* Wn2 = (const float*)d_in[11];
    const float* b2 = (const float*)d_in[12];
    const float* Wd1 = (const float*)d_in[13];
    const float* bd1 = (const float*)d_in[14];
    const float* Wd2 = (const float*)d_in[15];
    const float* bd2 = (const float*)d_in[16];
    const float* Wd3 = (const float*)d_in[17];
    const float* bd3 = (const float*)d_in[18];
    float* out = (float*)d_out;

    char* p = (char*)d_ws;
    int* deg = (int*)p;            p += alignup(N_NODES * 4);
    int* row_ptr = (int*)p;        p += alignup((N_NODES + 1) * 4);
    int* cursor = (int*)p;         p += alignup(N_NODES * 4);
    int* bsum = (int*)p;           p += alignup(64 * 4);
    int* colA = (int*)p;           p += alignup(N_EDGES * 4);
    unsigned short* A1 = (unsigned short*)p;  p += alignup((size_t)N_NODES * 256 * 2);
    unsigned short* A2 = (unsigned short*)p;  p += alignup((size_t)N_NODES * 256 * 2);
    unsigned short* h2b = (unsigned short*)p; p += alignup((size_t)N_NODES * 128 * 2);
    unsigned short* WT1 = (unsigned short*)p;  p += alignup(32768 * 2);
    unsigned short* WT2 = (unsigned short*)p;  p += alignup(32768 * 2);
    unsigned short* WdT1 = (unsigned short*)p; p += alignup(16384 * 2);
    unsigned short* WdT2 = (unsigned short*)p; p += alignup(16384 * 2);
    // z [200000,128] bf16 = 51.2 MB aliased onto A1+A2 (both dead after h2b written)
    unsigned short* z = A1;

    hipMemsetAsync(deg, 0, N_NODES * 4, stream);

    k_convert_x<<<(N_NODES * 32 + 255) / 256, 256, 0, stream>>>(x, A1);
    k_prep_w<<<384, 256, 0, stream>>>(Ws1, Wn1, Ws2, Wn2, Wd1, Wd2, WT1, WT2, WdT1, WdT2);

    k_deg<<<(N_EDGES + 255) / 256, 256, 0, stream>>>(edge_dst, deg);
    int nb1 = (N_NODES + 1023) / 1024;
    k_scan1<<<nb1, 1024, 0, stream>>>(deg, row_ptr, bsum, N_NODES);
    k_scan2<<<1, 1, 0, stream>>>(bsum, nb1);
    k_add<<<nb1, 1024, 0, stream>>>(row_ptr, cursor, bsum, N_NODES);
    k_scatter<<<(N_EDGES + 255) / 256, 256, 0, stream>>>(edge_src, edge_dst, cursor, colA);

    // layer 1
    k_agg<false><<<(N_NODES + 3) / 4, 256, 0, stream>>>(x, nullptr, 0, row_ptr, colA, A1 + 128, 256);
    k_gemm<<<(N_NODES + 63) / 64, 256, 0, stream>>>(A1, 256, 256, WT1, b1, A2, 256, N_NODES, 1);

    // layer 2
    k_agg<true><<<(N_NODES + 3) / 4, 256, 0, stream>>>(nullptr, A2, 256, row_ptr, colA, A2 + 128, 256);
    k_gemm<<<(N_NODES + 63) / 64, 256, 0, stream>>>(A2, 256, 256, WT2, b2, h2b, 128, N_NODES, 0);

    // decoder: gather z for pos+neg, then one fused MLP pass
    k_zgather<<<(N_PAIRS * 2 * 16) / 256, 256, 0, stream>>>(h2b, pos_src, pos_dst, neg_src, neg_dst, z);
    k_mlp<<<(N_PAIRS * 2) / 64, 256, 0, stream>>>(z, WdT1, WdT2, bd1, bd2, Wd3, bd3, out);
}

// Round 4
// 390.057 us; speedup vs baseline: 1.1645x; 1.1645x over previous
//
#include <hip/hip_runtime.h>
#include <hip/hip_bf16.h>

#define N_NODES 50000
#define N_EDGES 600000
#define N_PAIRS 100000

typedef __attribute__((ext_vector_type(8))) short bf16x8;
typedef __attribute__((ext_vector_type(4))) float f32x4;

__device__ inline unsigned short f2b(float f) {
    unsigned u = __float_as_uint(f);
    unsigned r = u + 0x7fff + ((u >> 16) & 1);
    return (unsigned short)(r >> 16);
}
__device__ inline float b2f(unsigned short h) {
    return __uint_as_float(((unsigned)h) << 16);
}

// ---- convert x (fp32 [N][128]) into A1[:, 0:128] bf16 (ld 256) ----
__global__ void k_convert_x(const float* __restrict__ x, unsigned short* __restrict__ A1) {
    int idx = blockIdx.x * blockDim.x + threadIdx.x;
    if (idx >= N_NODES * 32) return;
    int row = idx >> 5, c4 = (idx & 31) * 4;
    float4 v = *(const float4*)(x + row * 128 + c4);
    unsigned lo = (unsigned)f2b(v.x) | ((unsigned)f2b(v.y) << 16);
    unsigned hi = (unsigned)f2b(v.z) | ((unsigned)f2b(v.w) << 16);
    uint2 o; o.x = lo; o.y = hi;
    *(uint2*)(A1 + row * 256 + c4) = o;
}

// ---- build transposed bf16 weights ----
__global__ void k_prep_w(const float* __restrict__ Ws1, const float* __restrict__ Wn1,
                         const float* __restrict__ Ws2, const float* __restrict__ Wn2,
                         const float* __restrict__ Wd1, const float* __restrict__ Wd2,
                         unsigned short* __restrict__ WT1, unsigned short* __restrict__ WT2,
                         unsigned short* __restrict__ WdT1, unsigned short* __restrict__ WdT2) {
    int id = blockIdx.x * blockDim.x + threadIdx.x;
    if (id < 32768) {
        int k = id & 255, n = id >> 8;
        float v = (k < 128) ? Ws1[k * 128 + n] : Wn1[(k - 128) * 128 + n];
        WT1[n * 256 + k] = f2b(v);
    } else if (id < 65536) {
        int r = id - 32768; int k = r & 255, n = r >> 8;
        float v = (k < 128) ? Ws2[k * 128 + n] : Wn2[(k - 128) * 128 + n];
        WT2[n * 256 + k] = f2b(v);
    } else if (id < 81920) {
        int r = id - 65536; int k = r & 127, n = r >> 7;
        WdT1[n * 128 + k] = f2b(Wd1[k * 128 + n]);
    } else if (id < 98304) {
        int r = id - 81920; int k = r & 127, n = r >> 7;
        WdT2[n * 128 + k] = f2b(Wd2[k * 128 + n]);
    }
}

// ---- CSR build ----
__global__ void k_deg(const int* __restrict__ dst, int* __restrict__ deg) {
    int e = blockIdx.x * blockDim.x + threadIdx.x;
    if (e < N_EDGES) atomicAdd(&deg[dst[e]], 1);
}

__global__ void k_scan1(const int* __restrict__ deg, int* __restrict__ row_ptr,
                        int* __restrict__ bsum, int n) {
    __shared__ int tmp[1024];
    int i = blockIdx.x * 1024 + threadIdx.x;
    int d = (i < n) ? deg[i] : 0;
    tmp[threadIdx.x] = d;
    __syncthreads();
    int run = d;
    for (int off = 1; off < 1024; off <<= 1) {
        int t = (threadIdx.x >= off) ? tmp[threadIdx.x - off] : 0;
        __syncthreads();
        run += t;
        tmp[threadIdx.x] = run;
        __syncthreads();
    }
    if (i < n) row_ptr[i] = run - d;
    if (threadIdx.x == 1023) bsum[blockIdx.x] = run;
}

__global__ void k_scan2(int* __restrict__ bsum, int nb) {
    if (blockIdx.x == 0 && threadIdx.x == 0) {
        int acc = 0;
        for (int b = 0; b < nb; b++) { int t = bsum[b]; bsum[b] = acc; acc += t; }
    }
}

__global__ void k_add(int* __restrict__ row_ptr, int* __restrict__ cursor,
                      const int* __restrict__ bsum, int n) {
    int i = blockIdx.x * 1024 + threadIdx.x;
    if (i < n) {
        int v = row_ptr[i] + bsum[blockIdx.x];
        row_ptr[i] = v;
        cursor[i] = v;
    }
    if (i == 0) row_ptr[n] = N_EDGES;
}

__global__ void k_scatter(const int* __restrict__ src, const int* __restrict__ dst,
                          int* __restrict__ cursor, int* __restrict__ colA) {
    int e = blockIdx.x * blockDim.x + threadIdx.x;
    if (e < N_EDGES) {
        int d = dst[e];
        int slot = atomicAdd(&cursor[d], 1);
        colA[slot] = src[e];
    }
}

// ---- mean aggregation (R1 proven version): one wave per dst node, lane = 2 feats ----
template <bool BF16IN>
__global__ __launch_bounds__(256) void k_agg(const float* __restrict__ xf,
                                             const unsigned short* __restrict__ hb, int ldh,
                                             const int* __restrict__ row_ptr,
                                             const int* __restrict__ colA,
                                             unsigned short* __restrict__ outm, int ldo) {
    int w = (blockIdx.x * blockDim.x + threadIdx.x) >> 6;
    int lane = threadIdx.x & 63;
    if (w >= N_NODES) return;
    int s = row_ptr[w], e = row_ptr[w + 1];
    float a0 = 0.f, a1 = 0.f;
    for (int base = s; base < e; base += 64) {
        int ce = (base + lane < e) ? colA[base + lane] : 0;
        int cnt = min(64, e - base);
        int i = 0;
        for (; i + 1 < cnt; i += 2) {
            int s0 = __shfl(ce, i, 64);
            int s1 = __shfl(ce, i + 1, 64);
            if (BF16IN) {
                unsigned v0 = *(const unsigned*)(hb + s0 * ldh + 2 * lane);
                unsigned v1 = *(const unsigned*)(hb + s1 * ldh + 2 * lane);
                a0 += b2f(v0 & 0xffff) + b2f(v1 & 0xffff);
                a1 += b2f(v0 >> 16) + b2f(v1 >> 16);
            } else {
                float2 v0 = *(const float2*)(xf + s0 * 128 + 2 * lane);
                float2 v1 = *(const float2*)(xf + s1 * 128 + 2 * lane);
                a0 += v0.x + v1.x;
                a1 += v0.y + v1.y;
            }
        }
        if (i < cnt) {
            int s0 = __shfl(ce, i, 64);
            if (BF16IN) {
                unsigned v0 = *(const unsigned*)(hb + s0 * ldh + 2 * lane);
                a0 += b2f(v0 & 0xffff);
                a1 += b2f(v0 >> 16);
            } else {
                float2 v0 = *(const float2*)(xf + s0 * 128 + 2 * lane);
                a0 += v0.x;
                a1 += v0.y;
            }
        }
    }
    float rd = 1.0f / (float)max(e - s, 1);
    unsigned o = (unsigned)f2b(a0 * rd) | ((unsigned)f2b(a1 * rd) << 16);
    *(unsigned*)(outm + w * ldo + 2 * lane) = o;
}

// ---- SAGE layer GEMM v2: 32 rows/wave, weight frags grouped 8-in-flight ----
__global__ __launch_bounds__(256) void k_gemm(const unsigned short* __restrict__ A, int lda, int K,
                                              const unsigned short* __restrict__ BT,
                                              const float* __restrict__ bias,
                                              unsigned short* __restrict__ Hout, int ldo,
                                              int M, int relu) {
    int wv = threadIdx.x >> 6, lane = threadIdx.x & 63;
    int lr = lane & 15, lq = lane >> 4;
    int r0 = blockIdx.x * 128 + wv * 32;
    int arow0 = min(r0 + lr, M - 1);
    int arow1 = min(r0 + 16 + lr, M - 1);
    f32x4 acc[2][8];
    f32x4 zero = {0.f, 0.f, 0.f, 0.f};
#pragma unroll
    for (int m = 0; m < 2; m++)
#pragma unroll
        for (int ct = 0; ct < 8; ct++) acc[m][ct] = zero;
    for (int kb = 0; kb < K; kb += 32) {
        int ka = kb + lq * 8;
        bf16x8 wf[8];
#pragma unroll
        for (int ct = 0; ct < 8; ct++)
            wf[ct] = *(const bf16x8*)(BT + (ct * 16 + lr) * K + ka);
        bf16x8 af0 = *(const bf16x8*)(A + (size_t)arow0 * lda + ka);
        bf16x8 af1 = *(const bf16x8*)(A + (size_t)arow1 * lda + ka);
#pragma unroll
        for (int ct = 0; ct < 8; ct++) {
            acc[0][ct] = __builtin_amdgcn_mfma_f32_16x16x32_bf16(af0, wf[ct], acc[0][ct], 0, 0, 0);
            acc[1][ct] = __builtin_amdgcn_mfma_f32_16x16x32_bf16(af1, wf[ct], acc[1][ct], 0, 0, 0);
        }
    }
#pragma unroll
    for (int m = 0; m < 2; m++) {
#pragma unroll
        for (int ct = 0; ct < 8; ct++) {
            int colc = ct * 16 + lr;
            float bv = bias[colc];
#pragma unroll
            for (int r = 0; r < 4; r++) {
                int row = r0 + m * 16 + lq * 4 + r;
                if (row < M) {
                    float v = acc[m][ct][r] + bv;
                    if (relu) v = fmaxf(v, 0.f);
                    Hout[(size_t)row * ldo + colc] = f2b(v);
                }
            }
        }
    }
}

// ---- z gather: z[p] = h2b[src[p]] * h2b[dst[p]] (bf16), pos then neg ----
__global__ __launch_bounds__(256) void k_zgather(const unsigned short* __restrict__ h2b,
                                                 const int* __restrict__ pos_src,
                                                 const int* __restrict__ pos_dst,
                                                 const int* __restrict__ neg_src,
                                                 const int* __restrict__ neg_dst,
                                                 unsigned short* __restrict__ z) {
    int idx = blockIdx.x * 256 + threadIdx.x;
    int p = idx >> 4, c = idx & 15;
    int s, d;
    if (p < N_PAIRS) { s = pos_src[p]; d = pos_dst[p]; }
    else { s = neg_src[p - N_PAIRS]; d = neg_dst[p - N_PAIRS]; }
    uint4 av = *(const uint4*)(h2b + (size_t)s * 128 + c * 8);
    uint4 bv = *(const uint4*)(h2b + (size_t)d * 128 + c * 8);
    uint4 res;
    unsigned* rp = (unsigned*)&res;
    const unsigned* ap = (const unsigned*)&av;
    const unsigned* bp = (const unsigned*)&bv;
#pragma unroll
    for (int j = 0; j < 4; j++) {
        unsigned short lo = f2b(b2f(ap[j] & 0xffff) * b2f(bp[j] & 0xffff));
        unsigned short hi = f2b(b2f(ap[j] >> 16) * b2f(bp[j] >> 16));
        rp[j] = (unsigned)lo | ((unsigned)hi << 16);
    }
    *(uint4*)(z + (size_t)p * 128 + c * 8) = res;
}

// ---- decoder MLP v2: 32 rows/wave, weight frags grouped 8-in-flight ----
__global__ __launch_bounds__(256) void k_mlp(const unsigned short* __restrict__ z,
                                             const unsigned short* __restrict__ WdT1,
                                             const unsigned short* __restrict__ WdT2,
                                             const float* __restrict__ bd1,
                                             const float* __restrict__ bd2,
                                             const float* __restrict__ Wd3,
                                             const float* __restrict__ bd3,
                                             float* __restrict__ out, int P2) {
    __shared__ unsigned short t1[4][32][136];   // 34,816 B
    const int tid = threadIdx.x;
    const int wv = tid >> 6, lane = tid & 63, lr = lane & 15, lq = lane >> 4;
    const int row0 = blockIdx.x * 128 + wv * 32;
    f32x4 zero = {0.f, 0.f, 0.f, 0.f};
    f32x4 acc[2][8];
#pragma unroll
    for (int m = 0; m < 2; m++)
#pragma unroll
        for (int ct = 0; ct < 8; ct++) acc[m][ct] = zero;
    // layer 1: z @ Wd1
#pragma unroll
    for (int kb = 0; kb < 4; kb++) {
        int ka = kb * 32 + lq * 8;
        bf16x8 wf[8];
#pragma unroll
        for (int ct = 0; ct < 8; ct++)
            wf[ct] = *(const bf16x8*)(WdT1 + (ct * 16 + lr) * 128 + ka);
        bf16x8 af0 = *(const bf16x8*)(z + (size_t)(row0 + lr) * 128 + ka);
        bf16x8 af1 = *(const bf16x8*)(z + (size_t)(row0 + 16 + lr) * 128 + ka);
#pragma unroll
        for (int ct = 0; ct < 8; ct++) {
            acc[0][ct] = __builtin_amdgcn_mfma_f32_16x16x32_bf16(af0, wf[ct], acc[0][ct], 0, 0, 0);
            acc[1][ct] = __builtin_amdgcn_mfma_f32_16x16x32_bf16(af1, wf[ct], acc[1][ct], 0, 0, 0);
        }
    }
#pragma unroll
    for (int m = 0; m < 2; m++)
#pragma unroll
        for (int ct = 0; ct < 8; ct++) {
            int colc = ct * 16 + lr;
            float bv = bd1[colc];
#pragma unroll
            for (int r = 0; r < 4; r++) {
                float v = fmaxf(acc[m][ct][r] + bv, 0.f);
                t1[wv][m * 16 + lq * 4 + r][colc] = f2b(v);
            }
        }
    __syncthreads();
    // layer 2: t1 @ Wd2
#pragma unroll
    for (int m = 0; m < 2; m++)
#pragma unroll
        for (int ct = 0; ct < 8; ct++) acc[m][ct] = zero;
#pragma unroll
    for (int kb = 0; kb < 4; kb++) {
        int ka = kb * 32 + lq * 8;
        bf16x8 wf[8];
#pragma unroll
        for (int ct = 0; ct < 8; ct++)
            wf[ct] = *(const bf16x8*)(WdT2 + (ct * 16 + lr) * 128 + ka);
        bf16x8 af0 = *(const bf16x8*)(&t1[wv][lr][ka]);
        bf16x8 af1 = *(const bf16x8*)(&t1[wv][16 + lr][ka]);
#pragma unroll
        for (int ct = 0; ct < 8; ct++) {
            acc[0][ct] = __builtin_amdgcn_mfma_f32_16x16x32_bf16(af0, wf[ct], acc[0][ct], 0, 0, 0);
            acc[1][ct] = __builtin_amdgcn_mfma_f32_16x16x32_bf16(af1, wf[ct], acc[1][ct], 0, 0, 0);
        }
    }
    // layer 3: dot with Wd3 + reduce
    float sc[2][4] = {{0.f, 0.f, 0.f, 0.f}, {0.f, 0.f, 0.f, 0.f}};
#pragma unroll
    for (int ct = 0; ct < 8; ct++) {
        int colc = ct * 16 + lr;
        float bv = bd2[colc];
        float w3 = Wd3[colc];
#pragma unroll
        for (int m = 0; m < 2; m++)
#pragma unroll
            for (int r = 0; r < 4; r++) {
                float v = fmaxf(acc[m][ct][r] + bv, 0.f);
                sc[m][r] += v * w3;
            }
    }
#pragma unroll
    for (int mm = 1; mm < 16; mm <<= 1)
#pragma unroll
        for (int m = 0; m < 2; m++)
#pragma unroll
            for (int r = 0; r < 4; r++) sc[m][r] += __shfl_xor(sc[m][r], mm, 64);
    if (lr == 0) {
        float b3 = bd3[0];
#pragma unroll
        for (int m = 0; m < 2; m++)
#pragma unroll
            for (int r = 0; r < 4; r++) {
                int g = row0 + m * 16 + lq * 4 + r;
                if (g < P2) out[g] = sc[m][r] + b3;
            }
    }
}

static inline size_t alignup(size_t v) { return (v + 255) & ~(size_t)255; }

extern "C" void kernel_launch(void* const* d_in, const int* in_sizes, int n_in,
                              void* d_out, int out_size, void* d_ws, size_t ws_size,
                              hipStream_t stream) {
    const float* x = (const float*)d_in[0];
    const int* edge_src = (const int*)d_in[1];
    const int* edge_dst = (const int*)d_in[2];
    const int* pos_src = (const int*)d_in[3];
    const int* pos_dst = (const int*)d_in[4];
    const int* neg_src = (const int*)d_in[5];
    const int* neg_dst = (const int*)d_in[6];
    const float* Ws1 = (const float*)d_in[7];
    const float* Wn1 = (const float*)d_in[8];
    const float* b1 = (const float*)d_in[9];
    const float* Ws2 = (const float*)d_in[10];
    const float* Wn2 = (const float*)d_in[11];
    const float* b2 = (const float*)d_in[12];
    const float* Wd1 = (const float*)d_in[13];
    const float* bd1 = (const float*)d_in[14];
    const float* Wd2 = (const float*)d_in[15];
    const float* bd2 = (const float*)d_in[16];
    const float* Wd3 = (const float*)d_in[17];
    const float* bd3 = (const float*)d_in[18];
    float* out = (float*)d_out;

    char* p = (char*)d_ws;
    int* deg = (int*)p;            p += alignup(N_NODES * 4);
    int* row_ptr = (int*)p;        p += alignup((N_NODES + 1) * 4);
    int* cursor = (int*)p;         p += alignup(N_NODES * 4);
    int* bsum = (int*)p;           p += alignup(64 * 4);
    int* colA = (int*)p;           p += alignup(N_EDGES * 4);
    unsigned short* A1 = (unsigned short*)p;  p += alignup((size_t)N_NODES * 256 * 2);
    unsigned short* A2 = (unsigned short*)p;  p += alignup((size_t)N_NODES * 256 * 2);
    unsigned short* h2b = (unsigned short*)p; p += alignup((size_t)N_NODES * 128 * 2);
    unsigned short* WT1 = (unsigned short*)p;  p += alignup(32768 * 2);
    unsigned short* WT2 = (unsigned short*)p;  p += alignup(32768 * 2);
    unsigned short* WdT1 = (unsigned short*)p; p += alignup(16384 * 2);
    unsigned short* WdT2 = (unsigned short*)p; p += alignup(16384 * 2);
    // z [200000,128] bf16 = 51.2 MB aliased onto A1+A2 (both dead after h2b written)
    unsigned short* z = A1;

    hipMemsetAsync(deg, 0, N_NODES * 4, stream);

    k_convert_x<<<(N_NODES * 32 + 255) / 256, 256, 0, stream>>>(x, A1);
    k_prep_w<<<384, 256, 0, stream>>>(Ws1, Wn1, Ws2, Wn2, Wd1, Wd2, WT1, WT2, WdT1, WdT2);

    k_deg<<<(N_EDGES + 255) / 256, 256, 0, stream>>>(edge_dst, deg);
    int nb1 = (N_NODES + 1023) / 1024;
    k_scan1<<<nb1, 1024, 0, stream>>>(deg, row_ptr, bsum, N_NODES);
    k_scan2<<<1, 1, 0, stream>>>(bsum, nb1);
    k_add<<<nb1, 1024, 0, stream>>>(row_ptr, cursor, bsum, N_NODES);
    k_scatter<<<(N_EDGES + 255) / 256, 256, 0, stream>>>(edge_src, edge_dst, cursor, colA);

    // layer 1
    k_agg<false><<<(N_NODES + 3) / 4, 256, 0, stream>>>(x, nullptr, 0, row_ptr, colA, A1 + 128, 256);
    k_gemm<<<(N_NODES + 127) / 128, 256, 0, stream>>>(A1, 256, 256, WT1, b1, A2, 256, N_NODES, 1);

    // layer 2
    k_agg<true><<<(N_NODES + 3) / 4, 256, 0, stream>>>(nullptr, A2, 256, row_ptr, colA, A2 + 128, 256);
    k_gemm<<<(N_NODES + 127) / 128, 256, 0, stream>>>(A2, 256, 256, WT2, b2, h2b, 128, N_NODES, 0);

    // decoder: gather z for pos+neg, then one fused MLP pass
    k_zgather<<<(N_PAIRS * 2 * 16) / 256, 256, 0, stream>>>(h2b, pos_src, pos_dst, neg_src, neg_dst, z);
    k_mlp<<<(N_PAIRS * 2 + 127) / 128, 256, 0, stream>>>(z, WdT1, WdT2, bd1, bd2, Wd3, bd3, out, N_PAIRS * 2);
}

// Round 5
// 380.610 us; speedup vs baseline: 1.1934x; 1.0248x over previous
//
#include <hip/hip_runtime.h>
#include <hip/hip_bf16.h>

#define N_NODES 50000
#define N_EDGES 600000
#define N_PAIRS 100000

typedef __attribute__((ext_vector_type(8))) short bf16x8;
typedef __attribute__((ext_vector_type(4))) float f32x4;

__device__ inline unsigned short f2b(float f) {
    unsigned u = __float_as_uint(f);
    unsigned r = u + 0x7fff + ((u >> 16) & 1);
    return (unsigned short)(r >> 16);
}
__device__ inline float b2f(unsigned short h) {
    return __uint_as_float(((unsigned)h) << 16);
}

// ---- convert x (fp32 [N][128]) into A1[:, 0:128] bf16 (ld 256) ----
__global__ void k_convert_x(const float* __restrict__ x, unsigned short* __restrict__ A1) {
    int idx = blockIdx.x * blockDim.x + threadIdx.x;
    if (idx >= N_NODES * 32) return;
    int row = idx >> 5, c4 = (idx & 31) * 4;
    float4 v = *(const float4*)(x + row * 128 + c4);
    unsigned lo = (unsigned)f2b(v.x) | ((unsigned)f2b(v.y) << 16);
    unsigned hi = (unsigned)f2b(v.z) | ((unsigned)f2b(v.w) << 16);
    uint2 o; o.x = lo; o.y = hi;
    *(uint2*)(A1 + row * 256 + c4) = o;
}

// ---- build transposed bf16 weights ----
__global__ void k_prep_w(const float* __restrict__ Ws1, const float* __restrict__ Wn1,
                         const float* __restrict__ Ws2, const float* __restrict__ Wn2,
                         const float* __restrict__ Wd1, const float* __restrict__ Wd2,
                         unsigned short* __restrict__ WT1, unsigned short* __restrict__ WT2,
                         unsigned short* __restrict__ WdT1, unsigned short* __restrict__ WdT2) {
    int id = blockIdx.x * blockDim.x + threadIdx.x;
    if (id < 32768) {
        int k = id & 255, n = id >> 8;
        float v = (k < 128) ? Ws1[k * 128 + n] : Wn1[(k - 128) * 128 + n];
        WT1[n * 256 + k] = f2b(v);
    } else if (id < 65536) {
        int r = id - 32768; int k = r & 255, n = r >> 8;
        float v = (k < 128) ? Ws2[k * 128 + n] : Wn2[(k - 128) * 128 + n];
        WT2[n * 256 + k] = f2b(v);
    } else if (id < 81920) {
        int r = id - 65536; int k = r & 127, n = r >> 7;
        WdT1[n * 128 + k] = f2b(Wd1[k * 128 + n]);
    } else if (id < 98304) {
        int r = id - 81920; int k = r & 127, n = r >> 7;
        WdT2[n * 128 + k] = f2b(Wd2[k * 128 + n]);
    }
}

// ---- CSR build ----
__global__ void k_deg(const int* __restrict__ dst, int* __restrict__ deg) {
    int e = blockIdx.x * blockDim.x + threadIdx.x;
    if (e < N_EDGES) atomicAdd(&deg[dst[e]], 1);
}

__global__ void k_scan1(const int* __restrict__ deg, int* __restrict__ row_ptr,
                        int* __restrict__ bsum, int n) {
    __shared__ int tmp[1024];
    int i = blockIdx.x * 1024 + threadIdx.x;
    int d = (i < n) ? deg[i] : 0;
    tmp[threadIdx.x] = d;
    __syncthreads();
    int run = d;
    for (int off = 1; off < 1024; off <<= 1) {
        int t = (threadIdx.x >= off) ? tmp[threadIdx.x - off] : 0;
        __syncthreads();
        run += t;
        tmp[threadIdx.x] = run;
        __syncthreads();
    }
    if (i < n) row_ptr[i] = run - d;
    if (threadIdx.x == 1023) bsum[blockIdx.x] = run;
}

__global__ void k_scan2(int* __restrict__ bsum, int nb) {
    if (blockIdx.x == 0 && threadIdx.x == 0) {
        int acc = 0;
        for (int b = 0; b < nb; b++) { int t = bsum[b]; bsum[b] = acc; acc += t; }
    }
}

__global__ void k_add(int* __restrict__ row_ptr, int* __restrict__ cursor,
                      const int* __restrict__ bsum, int n) {
    int i = blockIdx.x * 1024 + threadIdx.x;
    if (i < n) {
        int v = row_ptr[i] + bsum[blockIdx.x];
        row_ptr[i] = v;
        cursor[i] = v;
    }
    if (i == 0) row_ptr[n] = N_EDGES;
}

__global__ void k_scatter(const int* __restrict__ src, const int* __restrict__ dst,
                          int* __restrict__ cursor, int* __restrict__ colA) {
    int e = blockIdx.x * blockDim.x + threadIdx.x;
    if (e < N_EDGES) {
        int d = dst[e];
        int slot = atomicAdd(&cursor[d], 1);
        colA[slot] = src[e];
    }
}

// ---- mean aggregation: one wave per dst node, lane = 2 feats.
// Bit-exact association with R1/R3: a += (v0+v1); a += (v2+v3); ...
// but 8 edges' loads hoisted per iteration for memory-level parallelism.
template <bool BF16IN>
__global__ __launch_bounds__(256) void k_agg(const float* __restrict__ xf,
                                             const unsigned short* __restrict__ hb, int ldh,
                                             const int* __restrict__ row_ptr,
                                             const int* __restrict__ colA,
                                             unsigned short* __restrict__ outm, int ldo) {
    int w = (blockIdx.x * blockDim.x + threadIdx.x) >> 6;
    int lane = threadIdx.x & 63;
    if (w >= N_NODES) return;
    int s = row_ptr[w], e = row_ptr[w + 1];
    float a0 = 0.f, a1 = 0.f;
    for (int base = s; base < e; base += 64) {
        int ce = (base + lane < e) ? colA[base + lane] : 0;
        int cnt = min(64, e - base);
        int i = 0;
        for (; i + 7 < cnt; i += 8) {
            int ei[8];
#pragma unroll
            for (int j = 0; j < 8; j++) ei[j] = __shfl(ce, i + j, 64);
            if (BF16IN) {
                unsigned v[8];
#pragma unroll
                for (int j = 0; j < 8; j++)
                    v[j] = *(const unsigned*)(hb + ei[j] * ldh + 2 * lane);
#pragma unroll
                for (int j = 0; j < 8; j += 2) {
                    a0 += b2f(v[j] & 0xffff) + b2f(v[j + 1] & 0xffff);
                    a1 += b2f(v[j] >> 16) + b2f(v[j + 1] >> 16);
                }
            } else {
                float2 v[8];
#pragma unroll
                for (int j = 0; j < 8; j++)
                    v[j] = *(const float2*)(xf + ei[j] * 128 + 2 * lane);
#pragma unroll
                for (int j = 0; j < 8; j += 2) {
                    a0 += v[j].x + v[j + 1].x;
                    a1 += v[j].y + v[j + 1].y;
                }
            }
        }
        for (; i + 1 < cnt; i += 2) {
            int s0 = __shfl(ce, i, 64);
            int s1 = __shfl(ce, i + 1, 64);
            if (BF16IN) {
                unsigned v0 = *(const unsigned*)(hb + s0 * ldh + 2 * lane);
                unsigned v1 = *(const unsigned*)(hb + s1 * ldh + 2 * lane);
                a0 += b2f(v0 & 0xffff) + b2f(v1 & 0xffff);
                a1 += b2f(v0 >> 16) + b2f(v1 >> 16);
            } else {
                float2 v0 = *(const float2*)(xf + s0 * 128 + 2 * lane);
                float2 v1 = *(const float2*)(xf + s1 * 128 + 2 * lane);
                a0 += v0.x + v1.x;
                a1 += v0.y + v1.y;
            }
        }
        if (i < cnt) {
            int s0 = __shfl(ce, i, 64);
            if (BF16IN) {
                unsigned v0 = *(const unsigned*)(hb + s0 * ldh + 2 * lane);
                a0 += b2f(v0 & 0xffff);
                a1 += b2f(v0 >> 16);
            } else {
                float2 v0 = *(const float2*)(xf + s0 * 128 + 2 * lane);
                a0 += v0.x;
                a1 += v0.y;
            }
        }
    }
    float rd = 1.0f / (float)max(e - s, 1);
    unsigned o = (unsigned)f2b(a0 * rd) | ((unsigned)f2b(a1 * rd) << 16);
    *(unsigned*)(outm + w * ldo + 2 * lane) = o;
}

// ---- SAGE layer GEMM: 32 rows/wave, weight frags grouped 8-in-flight ----
__global__ __launch_bounds__(256) void k_gemm(const unsigned short* __restrict__ A, int lda, int K,
                                              const unsigned short* __restrict__ BT,
                                              const float* __restrict__ bias,
                                              unsigned short* __restrict__ Hout, int ldo,
                                              int M, int relu) {
    int wv = threadIdx.x >> 6, lane = threadIdx.x & 63;
    int lr = lane & 15, lq = lane >> 4;
    int r0 = blockIdx.x * 128 + wv * 32;
    int arow0 = min(r0 + lr, M - 1);
    int arow1 = min(r0 + 16 + lr, M - 1);
    f32x4 acc[2][8];
    f32x4 zero = {0.f, 0.f, 0.f, 0.f};
#pragma unroll
    for (int m = 0; m < 2; m++)
#pragma unroll
        for (int ct = 0; ct < 8; ct++) acc[m][ct] = zero;
    for (int kb = 0; kb < K; kb += 32) {
        int ka = kb + lq * 8;
        bf16x8 wf[8];
#pragma unroll
        for (int ct = 0; ct < 8; ct++)
            wf[ct] = *(const bf16x8*)(BT + (ct * 16 + lr) * K + ka);
        bf16x8 af0 = *(const bf16x8*)(A + (size_t)arow0 * lda + ka);
        bf16x8 af1 = *(const bf16x8*)(A + (size_t)arow1 * lda + ka);
#pragma unroll
        for (int ct = 0; ct < 8; ct++) {
            acc[0][ct] = __builtin_amdgcn_mfma_f32_16x16x32_bf16(af0, wf[ct], acc[0][ct], 0, 0, 0);
            acc[1][ct] = __builtin_amdgcn_mfma_f32_16x16x32_bf16(af1, wf[ct], acc[1][ct], 0, 0, 0);
        }
    }
#pragma unroll
    for (int m = 0; m < 2; m++) {
#pragma unroll
        for (int ct = 0; ct < 8; ct++) {
            int colc = ct * 16 + lr;
            float bv = bias[colc];
#pragma unroll
            for (int r = 0; r < 4; r++) {
                int row = r0 + m * 16 + lq * 4 + r;
                if (row < M) {
                    float v = acc[m][ct][r] + bv;
                    if (relu) v = fmaxf(v, 0.f);
                    Hout[(size_t)row * ldo + colc] = f2b(v);
                }
            }
        }
    }
}

// ---- decoder MLP v3: fused z-gather in registers + 32 rows/wave MFMA MLP ----
__global__ __launch_bounds__(256) void k_mlp(const unsigned short* __restrict__ h2b,
                                             const int* __restrict__ pos_src,
                                             const int* __restrict__ pos_dst,
                                             const int* __restrict__ neg_src,
                                             const int* __restrict__ neg_dst,
                                             const unsigned short* __restrict__ WdT1,
                                             const unsigned short* __restrict__ WdT2,
                                             const float* __restrict__ bd1,
                                             const float* __restrict__ bd2,
                                             const float* __restrict__ Wd3,
                                             const float* __restrict__ bd3,
                                             float* __restrict__ out, int P2) {
    __shared__ unsigned short t1[4][32][136];   // 34,816 B
    const int tid = threadIdx.x;
    const int wv = tid >> 6, lane = tid & 63, lr = lane & 15, lq = lane >> 4;
    const int row0 = blockIdx.x * 128 + wv * 32;
    // pair indices for this lane's two A-rows
    int p0 = min(row0 + lr, P2 - 1);
    int p1 = min(row0 + 16 + lr, P2 - 1);
    int s0i = (p0 < N_PAIRS) ? pos_src[p0] : neg_src[p0 - N_PAIRS];
    int d0i = (p0 < N_PAIRS) ? pos_dst[p0] : neg_dst[p0 - N_PAIRS];
    int s1i = (p1 < N_PAIRS) ? pos_src[p1] : neg_src[p1 - N_PAIRS];
    int d1i = (p1 < N_PAIRS) ? pos_dst[p1] : neg_dst[p1 - N_PAIRS];
    // gather both rows of both tiles: 16 outstanding 16B loads
    uint4 za0[4], zb0[4], za1[4], zb1[4];
#pragma unroll
    for (int kb = 0; kb < 4; kb++) {
        int ka = kb * 32 + lq * 8;
        za0[kb] = *(const uint4*)(h2b + (size_t)s0i * 128 + ka);
        zb0[kb] = *(const uint4*)(h2b + (size_t)d0i * 128 + ka);
        za1[kb] = *(const uint4*)(h2b + (size_t)s1i * 128 + ka);
        zb1[kb] = *(const uint4*)(h2b + (size_t)d1i * 128 + ka);
    }
    // z = hs * hd, rounded to bf16 (bit-identical to the old zgather output)
    bf16x8 af0[4], af1[4];
#pragma unroll
    for (int kb = 0; kb < 4; kb++) {
        unsigned r0v[4], r1v[4];
        const unsigned* a0p = (const unsigned*)&za0[kb];
        const unsigned* b0p = (const unsigned*)&zb0[kb];
        const unsigned* a1p = (const unsigned*)&za1[kb];
        const unsigned* b1p = (const unsigned*)&zb1[kb];
#pragma unroll
        for (int j = 0; j < 4; j++) {
            unsigned short lo0 = f2b(b2f(a0p[j] & 0xffff) * b2f(b0p[j] & 0xffff));
            unsigned short hi0 = f2b(b2f(a0p[j] >> 16) * b2f(b0p[j] >> 16));
            r0v[j] = (unsigned)lo0 | ((unsigned)hi0 << 16);
            unsigned short lo1 = f2b(b2f(a1p[j] & 0xffff) * b2f(b1p[j] & 0xffff));
            unsigned short hi1 = f2b(b2f(a1p[j] >> 16) * b2f(b1p[j] >> 16));
            r1v[j] = (unsigned)lo1 | ((unsigned)hi1 << 16);
        }
        af0[kb] = *(const bf16x8*)r0v;
        af1[kb] = *(const bf16x8*)r1v;
    }
    f32x4 zero = {0.f, 0.f, 0.f, 0.f};
    f32x4 acc[2][8];
#pragma unroll
    for (int m = 0; m < 2; m++)
#pragma unroll
        for (int ct = 0; ct < 8; ct++) acc[m][ct] = zero;
    // layer 1: z @ Wd1
#pragma unroll
    for (int kb = 0; kb < 4; kb++) {
        int ka = kb * 32 + lq * 8;
        bf16x8 wf[8];
#pragma unroll
        for (int ct = 0; ct < 8; ct++)
            wf[ct] = *(const bf16x8*)(WdT1 + (ct * 16 + lr) * 128 + ka);
#pragma unroll
        for (int ct = 0; ct < 8; ct++) {
            acc[0][ct] = __builtin_amdgcn_mfma_f32_16x16x32_bf16(af0[kb], wf[ct], acc[0][ct], 0, 0, 0);
            acc[1][ct] = __builtin_amdgcn_mfma_f32_16x16x32_bf16(af1[kb], wf[ct], acc[1][ct], 0, 0, 0);
        }
    }
#pragma unroll
    for (int m = 0; m < 2; m++)
#pragma unroll
        for (int ct = 0; ct < 8; ct++) {
            int colc = ct * 16 + lr;
            float bv = bd1[colc];
#pragma unroll
            for (int r = 0; r < 4; r++) {
                float v = fmaxf(acc[m][ct][r] + bv, 0.f);
                t1[wv][m * 16 + lq * 4 + r][colc] = f2b(v);
            }
        }
    __syncthreads();
    // layer 2: t1 @ Wd2
#pragma unroll
    for (int m = 0; m < 2; m++)
#pragma unroll
        for (int ct = 0; ct < 8; ct++) acc[m][ct] = zero;
#pragma unroll
    for (int kb = 0; kb < 4; kb++) {
        int ka = kb * 32 + lq * 8;
        bf16x8 wf[8];
#pragma unroll
        for (int ct = 0; ct < 8; ct++)
            wf[ct] = *(const bf16x8*)(WdT2 + (ct * 16 + lr) * 128 + ka);
        bf16x8 bf0 = *(const bf16x8*)(&t1[wv][lr][ka]);
        bf16x8 bf1 = *(const bf16x8*)(&t1[wv][16 + lr][ka]);
#pragma unroll
        for (int ct = 0; ct < 8; ct++) {
            acc[0][ct] = __builtin_amdgcn_mfma_f32_16x16x32_bf16(bf0, wf[ct], acc[0][ct], 0, 0, 0);
            acc[1][ct] = __builtin_amdgcn_mfma_f32_16x16x32_bf16(bf1, wf[ct], acc[1][ct], 0, 0, 0);
        }
    }
    // layer 3: dot with Wd3 + reduce
    float sc[2][4] = {{0.f, 0.f, 0.f, 0.f}, {0.f, 0.f, 0.f, 0.f}};
#pragma unroll
    for (int ct = 0; ct < 8; ct++) {
        int colc = ct * 16 + lr;
        float bv = bd2[colc];
        float w3 = Wd3[colc];
#pragma unroll
        for (int m = 0; m < 2; m++)
#pragma unroll
            for (int r = 0; r < 4; r++) {
                float v = fmaxf(acc[m][ct][r] + bv, 0.f);
                sc[m][r] += v * w3;
            }
    }
#pragma unroll
    for (int mm = 1; mm < 16; mm <<= 1)
#pragma unroll
        for (int m = 0; m < 2; m++)
#pragma unroll
            for (int r = 0; r < 4; r++) sc[m][r] += __shfl_xor(sc[m][r], mm, 64);
    if (lr == 0) {
        float b3 = bd3[0];
#pragma unroll
        for (int m = 0; m < 2; m++)
#pragma unroll
            for (int r = 0; r < 4; r++) {
                int g = row0 + m * 16 + lq * 4 + r;
                if (g < P2) out[g] = sc[m][r] + b3;
            }
    }
}

static inline size_t alignup(size_t v) { return (v + 255) & ~(size_t)255; }

extern "C" void kernel_launch(void* const* d_in, const int* in_sizes, int n_in,
                              void* d_out, int out_size, void* d_ws, size_t ws_size,
                              hipStream_t stream) {
    const float* x = (const float*)d_in[0];
    const int* edge_src = (const int*)d_in[1];
    const int* edge_dst = (const int*)d_in[2];
    const int* pos_src = (const int*)d_in[3];
    const int* pos_dst = (const int*)d_in[4];
    const int* neg_src = (const int*)d_in[5];
    const int* neg_dst = (const int*)d_in[6];
    const float* Ws1 = (const float*)d_in[7];
    const float* Wn1 = (const float*)d_in[8];
    const float* b1 = (const float*)d_in[9];
    const float* Ws2 = (const float*)d_in[10];
    const float* Wn2 = (const float*)d_in[11];
    const float* b2 = (const float*)d_in[12];
    const float* Wd1 = (const float*)d_in[13];
    const float* bd1 = (const float*)d_in[14];
    const float* Wd2 = (const float*)d_in[15];
    const float* bd2 = (const float*)d_in[16];
    const float* Wd3 = (const float*)d_in[17];
    const float* bd3 = (const float*)d_in[18];
    float* out = (float*)d_out;

    char* p = (char*)d_ws;
    int* deg = (int*)p;            p += alignup(N_NODES * 4);
    int* row_ptr = (int*)p;        p += alignup((N_NODES + 1) * 4);
    int* cursor = (int*)p;         p += alignup(N_NODES * 4);
    int* bsum = (int*)p;           p += alignup(64 * 4);
    int* colA = (int*)p;           p += alignup(N_EDGES * 4);
    unsigned short* A1 = (unsigned short*)p;  p += alignup((size_t)N_NODES * 256 * 2);
    unsigned short* A2 = (unsigned short*)p;  p += alignup((size_t)N_NODES * 256 * 2);
    unsigned short* h2b = (unsigned short*)p; p += alignup((size_t)N_NODES * 128 * 2);
    unsigned short* WT1 = (unsigned short*)p;  p += alignup(32768 * 2);
    unsigned short* WT2 = (unsigned short*)p;  p += alignup(32768 * 2);
    unsigned short* WdT1 = (unsigned short*)p; p += alignup(16384 * 2);
    unsigned short* WdT2 = (unsigned short*)p; p += alignup(16384 * 2);

    hipMemsetAsync(deg, 0, N_NODES * 4, stream);

    k_convert_x<<<(N_NODES * 32 + 255) / 256, 256, 0, stream>>>(x, A1);
    k_prep_w<<<384, 256, 0, stream>>>(Ws1, Wn1, Ws2, Wn2, Wd1, Wd2, WT1, WT2, WdT1, WdT2);

    k_deg<<<(N_EDGES + 255) / 256, 256, 0, stream>>>(edge_dst, deg);
    int nb1 = (N_NODES + 1023) / 1024;
    k_scan1<<<nb1, 1024, 0, stream>>>(deg, row_ptr, bsum, N_NODES);
    k_scan2<<<1, 1, 0, stream>>>(bsum, nb1);
    k_add<<<nb1, 1024, 0, stream>>>(row_ptr, cursor, bsum, N_NODES);
    k_scatter<<<(N_EDGES + 255) / 256, 256, 0, stream>>>(edge_src, edge_dst, cursor, colA);

    // layer 1
    k_agg<false><<<(N_NODES + 3) / 4, 256, 0, stream>>>(x, nullptr, 0, row_ptr, colA, A1 + 128, 256);
    k_gemm<<<(N_NODES + 127) / 128, 256, 0, stream>>>(A1, 256, 256, WT1, b1, A2, 256, N_NODES, 1);

    // layer 2
    k_agg<true><<<(N_NODES + 3) / 4, 256, 0, stream>>>(nullptr, A2, 256, row_ptr, colA, A2 + 128, 256);
    k_gemm<<<(N_NODES + 127) / 128, 256, 0, stream>>>(A2, 256, 256, WT2, b2, h2b, 128, N_NODES, 0);

    // decoder: fused gather + MLP, pos and neg in one launch
    k_mlp<<<(N_PAIRS * 2 + 127) / 128, 256, 0, stream>>>(h2b, pos_src, pos_dst, neg_src, neg_dst,
                                                         WdT1, WdT2, bd1, bd2, Wd3, bd3,
                                                         out, N_PAIRS * 2);
}

// Round 6
// 363.063 us; speedup vs baseline: 1.2511x; 1.0483x over previous
//
#include <hip/hip_runtime.h>
#include <hip/hip_bf16.h>

#define N_NODES 50000
#define N_EDGES 600000
#define N_PAIRS 100000

typedef __attribute__((ext_vector_type(8))) short bf16x8;
typedef __attribute__((ext_vector_type(4))) float f32x4;

__device__ inline unsigned short f2b(float f) {
    unsigned u = __float_as_uint(f);
    unsigned r = u + 0x7fff + ((u >> 16) & 1);
    return (unsigned short)(r >> 16);
}
__device__ inline float b2f(unsigned short h) {
    return __uint_as_float(((unsigned)h) << 16);
}

// ---- convert x (fp32 [N][128]) into A1[:, 0:128] bf16 (ld 256) ----
__global__ void k_convert_x(const float* __restrict__ x, unsigned short* __restrict__ A1) {
    int idx = blockIdx.x * blockDim.x + threadIdx.x;
    if (idx >= N_NODES * 32) return;
    int row = idx >> 5, c4 = (idx & 31) * 4;
    float4 v = *(const float4*)(x + row * 128 + c4);
    unsigned lo = (unsigned)f2b(v.x) | ((unsigned)f2b(v.y) << 16);
    unsigned hi = (unsigned)f2b(v.z) | ((unsigned)f2b(v.w) << 16);
    uint2 o; o.x = lo; o.y = hi;
    *(uint2*)(A1 + row * 256 + c4) = o;
}

// ---- build transposed bf16 weights ----
__global__ void k_prep_w(const float* __restrict__ Ws1, const float* __restrict__ Wn1,
                         const float* __restrict__ Ws2, const float* __restrict__ Wn2,
                         const float* __restrict__ Wd1, const float* __restrict__ Wd2,
                         unsigned short* __restrict__ WT1, unsigned short* __restrict__ WT2,
                         unsigned short* __restrict__ WdT1, unsigned short* __restrict__ WdT2) {
    int id = blockIdx.x * blockDim.x + threadIdx.x;
    if (id < 32768) {
        int k = id & 255, n = id >> 8;
        float v = (k < 128) ? Ws1[k * 128 + n] : Wn1[(k - 128) * 128 + n];
        WT1[n * 256 + k] = f2b(v);
    } else if (id < 65536) {
        int r = id - 32768; int k = r & 255, n = r >> 8;
        float v = (k < 128) ? Ws2[k * 128 + n] : Wn2[(k - 128) * 128 + n];
        WT2[n * 256 + k] = f2b(v);
    } else if (id < 81920) {
        int r = id - 65536; int k = r & 127, n = r >> 7;
        WdT1[n * 128 + k] = f2b(Wd1[k * 128 + n]);
    } else if (id < 98304) {
        int r = id - 81920; int k = r & 127, n = r >> 7;
        WdT2[n * 128 + k] = f2b(Wd2[k * 128 + n]);
    }
}

// ---- CSR build ----
__global__ void k_deg(const int* __restrict__ dst, int* __restrict__ deg) {
    int e = blockIdx.x * blockDim.x + threadIdx.x;
    if (e < N_EDGES) atomicAdd(&deg[dst[e]], 1);
}

__global__ void k_scan1(const int* __restrict__ deg, int* __restrict__ row_ptr,
                        int* __restrict__ bsum, int n) {
    __shared__ int tmp[1024];
    int i = blockIdx.x * 1024 + threadIdx.x;
    int d = (i < n) ? deg[i] : 0;
    tmp[threadIdx.x] = d;
    __syncthreads();
    int run = d;
    for (int off = 1; off < 1024; off <<= 1) {
        int t = (threadIdx.x >= off) ? tmp[threadIdx.x - off] : 0;
        __syncthreads();
        run += t;
        tmp[threadIdx.x] = run;
        __syncthreads();
    }
    if (i < n) row_ptr[i] = run - d;
    if (threadIdx.x == 1023) bsum[blockIdx.x] = run;
}

__global__ void k_scan2(int* __restrict__ bsum, int nb) {
    if (blockIdx.x == 0 && threadIdx.x == 0) {
        int acc = 0;
        for (int b = 0; b < nb; b++) { int t = bsum[b]; bsum[b] = acc; acc += t; }
    }
}

__global__ void k_add(int* __restrict__ row_ptr, int* __restrict__ cursor,
                      const int* __restrict__ bsum, int n) {
    int i = blockIdx.x * 1024 + threadIdx.x;
    if (i < n) {
        int v = row_ptr[i] + bsum[blockIdx.x];
        row_ptr[i] = v;
        cursor[i] = v;
    }
    if (i == 0) row_ptr[n] = N_EDGES;
}

__global__ void k_scatter(const int* __restrict__ src, const int* __restrict__ dst,
                          int* __restrict__ cursor, int* __restrict__ colA) {
    int e = blockIdx.x * blockDim.x + threadIdx.x;
    if (e < N_EDGES) {
        int d = dst[e];
        int slot = atomicAdd(&cursor[d], 1);
        colA[slot] = src[e];
    }
}

// ---- mean aggregation v3: 2 nodes per wave (half-wave each), lane = 4 feats.
// Bit-exact association with R1/R4: per feature, edges added pairwise
// (e0+e1),(e2+e3),... in increasing edge order; chunk=32 keeps pairs aligned.
// All 8 loads of each block hoisted (predicated via index clamp) for MLP.
template <bool BF16IN>
__global__ __launch_bounds__(256) void k_agg(const float* __restrict__ xf,
                                             const unsigned short* __restrict__ hb, int ldh,
                                             const int* __restrict__ row_ptr,
                                             const int* __restrict__ colA,
                                             unsigned short* __restrict__ outm, int ldo) {
    int wave = (blockIdx.x * blockDim.x + threadIdx.x) >> 6;
    int lane = threadIdx.x & 63;
    int half = lane >> 5, hl = lane & 31;
    int w = wave * 2 + half;
    if (w >= N_NODES) return;
    int s = row_ptr[w], e = row_ptr[w + 1];
    float a0 = 0.f, a1 = 0.f, a2 = 0.f, a3 = 0.f;
    for (int base = s; base < e; base += 32) {
        int ce = (base + hl < e) ? colA[base + hl] : 0;
        int cnt = min(32, e - base);
        for (int i = 0; i < cnt; i += 8) {
            int ei[8];
#pragma unroll
            for (int j = 0; j < 8; j++) {
                int jj = i + j;
                int sl = (jj < cnt) ? jj : (cnt - 1);
                ei[j] = __shfl(ce, (half << 5) + sl, 64);
            }
            if (BF16IN) {
                uint2 v[8];
#pragma unroll
                for (int j = 0; j < 8; j++)
                    v[j] = *(const uint2*)(hb + (size_t)ei[j] * ldh + 4 * hl);
#pragma unroll
                for (int j = 0; j < 8; j += 2) {
                    if (i + j + 1 < cnt) {
                        a0 += b2f(v[j].x & 0xffff) + b2f(v[j + 1].x & 0xffff);
                        a1 += b2f(v[j].x >> 16) + b2f(v[j + 1].x >> 16);
                        a2 += b2f(v[j].y & 0xffff) + b2f(v[j + 1].y & 0xffff);
                        a3 += b2f(v[j].y >> 16) + b2f(v[j + 1].y >> 16);
                    } else if (i + j < cnt) {
                        a0 += b2f(v[j].x & 0xffff);
                        a1 += b2f(v[j].x >> 16);
                        a2 += b2f(v[j].y & 0xffff);
                        a3 += b2f(v[j].y >> 16);
                    }
                }
            } else {
                float4 v[8];
#pragma unroll
                for (int j = 0; j < 8; j++)
                    v[j] = *(const float4*)(xf + (size_t)ei[j] * 128 + 4 * hl);
#pragma unroll
                for (int j = 0; j < 8; j += 2) {
                    if (i + j + 1 < cnt) {
                        a0 += v[j].x + v[j + 1].x;
                        a1 += v[j].y + v[j + 1].y;
                        a2 += v[j].z + v[j + 1].z;
                        a3 += v[j].w + v[j + 1].w;
                    } else if (i + j < cnt) {
                        a0 += v[j].x;
                        a1 += v[j].y;
                        a2 += v[j].z;
                        a3 += v[j].w;
                    }
                }
            }
        }
    }
    float rd = 1.0f / (float)max(e - s, 1);
    uint2 o;
    o.x = (unsigned)f2b(a0 * rd) | ((unsigned)f2b(a1 * rd) << 16);
    o.y = (unsigned)f2b(a2 * rd) | ((unsigned)f2b(a3 * rd) << 16);
    *(uint2*)(outm + (size_t)w * ldo + 4 * hl) = o;
}

// ---- SAGE layer GEMM: 32 rows/wave, weight frags grouped 8-in-flight ----
__global__ __launch_bounds__(256) void k_gemm(const unsigned short* __restrict__ A, int lda, int K,
                                              const unsigned short* __restrict__ BT,
                                              const float* __restrict__ bias,
                                              unsigned short* __restrict__ Hout, int ldo,
                                              int M, int relu) {
    int wv = threadIdx.x >> 6, lane = threadIdx.x & 63;
    int lr = lane & 15, lq = lane >> 4;
    int r0 = blockIdx.x * 128 + wv * 32;
    int arow0 = min(r0 + lr, M - 1);
    int arow1 = min(r0 + 16 + lr, M - 1);
    f32x4 acc[2][8];
    f32x4 zero = {0.f, 0.f, 0.f, 0.f};
#pragma unroll
    for (int m = 0; m < 2; m++)
#pragma unroll
        for (int ct = 0; ct < 8; ct++) acc[m][ct] = zero;
    for (int kb = 0; kb < K; kb += 32) {
        int ka = kb + lq * 8;
        bf16x8 wf[8];
#pragma unroll
        for (int ct = 0; ct < 8; ct++)
            wf[ct] = *(const bf16x8*)(BT + (ct * 16 + lr) * K + ka);
        bf16x8 af0 = *(const bf16x8*)(A + (size_t)arow0 * lda + ka);
        bf16x8 af1 = *(const bf16x8*)(A + (size_t)arow1 * lda + ka);
#pragma unroll
        for (int ct = 0; ct < 8; ct++) {
            acc[0][ct] = __builtin_amdgcn_mfma_f32_16x16x32_bf16(af0, wf[ct], acc[0][ct], 0, 0, 0);
            acc[1][ct] = __builtin_amdgcn_mfma_f32_16x16x32_bf16(af1, wf[ct], acc[1][ct], 0, 0, 0);
        }
    }
#pragma unroll
    for (int m = 0; m < 2; m++) {
#pragma unroll
        for (int ct = 0; ct < 8; ct++) {
            int colc = ct * 16 + lr;
            float bv = bias[colc];
#pragma unroll
            for (int r = 0; r < 4; r++) {
                int row = r0 + m * 16 + lq * 4 + r;
                if (row < M) {
                    float v = acc[m][ct][r] + bv;
                    if (relu) v = fmaxf(v, 0.f);
                    Hout[(size_t)row * ldo + colc] = f2b(v);
                }
            }
        }
    }
}

// ---- decoder MLP v4: 128-thread blocks (2 waves), fused register gather ----
__global__ __launch_bounds__(128) void k_mlp(const unsigned short* __restrict__ h2b,
                                             const int* __restrict__ pos_src,
                                             const int* __restrict__ pos_dst,
                                             const int* __restrict__ neg_src,
                                             const int* __restrict__ neg_dst,
                                             const unsigned short* __restrict__ WdT1,
                                             const unsigned short* __restrict__ WdT2,
                                             const float* __restrict__ bd1,
                                             const float* __restrict__ bd2,
                                             const float* __restrict__ Wd3,
                                             const float* __restrict__ bd3,
                                             float* __restrict__ out, int P2) {
    __shared__ unsigned short t1[2][32][136];   // 17,408 B -> 9 blocks/CU by LDS
    const int tid = threadIdx.x;
    const int wv = tid >> 6, lane = tid & 63, lr = lane & 15, lq = lane >> 4;
    const int row0 = blockIdx.x * 64 + wv * 32;
    int p0 = min(row0 + lr, P2 - 1);
    int p1 = min(row0 + 16 + lr, P2 - 1);
    int s0i = (p0 < N_PAIRS) ? pos_src[p0] : neg_src[p0 - N_PAIRS];
    int d0i = (p0 < N_PAIRS) ? pos_dst[p0] : neg_dst[p0 - N_PAIRS];
    int s1i = (p1 < N_PAIRS) ? pos_src[p1] : neg_src[p1 - N_PAIRS];
    int d1i = (p1 < N_PAIRS) ? pos_dst[p1] : neg_dst[p1 - N_PAIRS];
    // gather both rows of both tiles: 16 outstanding 16B loads
    uint4 za0[4], zb0[4], za1[4], zb1[4];
#pragma unroll
    for (int kb = 0; kb < 4; kb++) {
        int ka = kb * 32 + lq * 8;
        za0[kb] = *(const uint4*)(h2b + (size_t)s0i * 128 + ka);
        zb0[kb] = *(const uint4*)(h2b + (size_t)d0i * 128 + ka);
        za1[kb] = *(const uint4*)(h2b + (size_t)s1i * 128 + ka);
        zb1[kb] = *(const uint4*)(h2b + (size_t)d1i * 128 + ka);
    }
    // z = hs * hd, rounded to bf16 (bit-identical to discrete zgather)
    bf16x8 af0[4], af1[4];
#pragma unroll
    for (int kb = 0; kb < 4; kb++) {
        unsigned r0v[4], r1v[4];
        const unsigned* a0p = (const unsigned*)&za0[kb];
        const unsigned* b0p = (const unsigned*)&zb0[kb];
        const unsigned* a1p = (const unsigned*)&za1[kb];
        const unsigned* b1p = (const unsigned*)&zb1[kb];
#pragma unroll
        for (int j = 0; j < 4; j++) {
            unsigned short lo0 = f2b(b2f(a0p[j] & 0xffff) * b2f(b0p[j] & 0xffff));
            unsigned short hi0 = f2b(b2f(a0p[j] >> 16) * b2f(b0p[j] >> 16));
            r0v[j] = (unsigned)lo0 | ((unsigned)hi0 << 16);
            unsigned short lo1 = f2b(b2f(a1p[j] & 0xffff) * b2f(b1p[j] & 0xffff));
            unsigned short hi1 = f2b(b2f(a1p[j] >> 16) * b2f(b1p[j] >> 16));
            r1v[j] = (unsigned)lo1 | ((unsigned)hi1 << 16);
        }
        af0[kb] = *(const bf16x8*)r0v;
        af1[kb] = *(const bf16x8*)r1v;
    }
    f32x4 zero = {0.f, 0.f, 0.f, 0.f};
    f32x4 acc[2][8];
#pragma unroll
    for (int m = 0; m < 2; m++)
#pragma unroll
        for (int ct = 0; ct < 8; ct++) acc[m][ct] = zero;
    // layer 1: z @ Wd1
#pragma unroll
    for (int kb = 0; kb < 4; kb++) {
        int ka = kb * 32 + lq * 8;
        bf16x8 wf[8];
#pragma unroll
        for (int ct = 0; ct < 8; ct++)
            wf[ct] = *(const bf16x8*)(WdT1 + (ct * 16 + lr) * 128 + ka);
#pragma unroll
        for (int ct = 0; ct < 8; ct++) {
            acc[0][ct] = __builtin_amdgcn_mfma_f32_16x16x32_bf16(af0[kb], wf[ct], acc[0][ct], 0, 0, 0);
            acc[1][ct] = __builtin_amdgcn_mfma_f32_16x16x32_bf16(af1[kb], wf[ct], acc[1][ct], 0, 0, 0);
        }
    }
#pragma unroll
    for (int m = 0; m < 2; m++)
#pragma unroll
        for (int ct = 0; ct < 8; ct++) {
            int colc = ct * 16 + lr;
            float bv = bd1[colc];
#pragma unroll
            for (int r = 0; r < 4; r++) {
                float v = fmaxf(acc[m][ct][r] + bv, 0.f);
                t1[wv][m * 16 + lq * 4 + r][colc] = f2b(v);
            }
        }
    __syncthreads();
    // layer 2: t1 @ Wd2
#pragma unroll
    for (int m = 0; m < 2; m++)
#pragma unroll
        for (int ct = 0; ct < 8; ct++) acc[m][ct] = zero;
#pragma unroll
    for (int kb = 0; kb < 4; kb++) {
        int ka = kb * 32 + lq * 8;
        bf16x8 wf[8];
#pragma unroll
        for (int ct = 0; ct < 8; ct++)
            wf[ct] = *(const bf16x8*)(WdT2 + (ct * 16 + lr) * 128 + ka);
        bf16x8 bf0 = *(const bf16x8*)(&t1[wv][lr][ka]);
        bf16x8 bf1 = *(const bf16x8*)(&t1[wv][16 + lr][ka]);
#pragma unroll
        for (int ct = 0; ct < 8; ct++) {
            acc[0][ct] = __builtin_amdgcn_mfma_f32_16x16x32_bf16(bf0, wf[ct], acc[0][ct], 0, 0, 0);
            acc[1][ct] = __builtin_amdgcn_mfma_f32_16x16x32_bf16(bf1, wf[ct], acc[1][ct], 0, 0, 0);
        }
    }
    // layer 3: dot with Wd3 + reduce
    float sc[2][4] = {{0.f, 0.f, 0.f, 0.f}, {0.f, 0.f, 0.f, 0.f}};
#pragma unroll
    for (int ct = 0; ct < 8; ct++) {
        int colc = ct * 16 + lr;
        float bv = bd2[colc];
        float w3 = Wd3[colc];
#pragma unroll
        for (int m = 0; m < 2; m++)
#pragma unroll
            for (int r = 0; r < 4; r++) {
                float v = fmaxf(acc[m][ct][r] + bv, 0.f);
                sc[m][r] += v * w3;
            }
    }
#pragma unroll
    for (int mm = 1; mm < 16; mm <<= 1)
#pragma unroll
        for (int m = 0; m < 2; m++)
#pragma unroll
            for (int r = 0; r < 4; r++) sc[m][r] += __shfl_xor(sc[m][r], mm, 64);
    if (lr == 0) {
        float b3 = bd3[0];
#pragma unroll
        for (int m = 0; m < 2; m++)
#pragma unroll
            for (int r = 0; r < 4; r++) {
                int g = row0 + m * 16 + lq * 4 + r;
                if (g < P2) out[g] = sc[m][r] + b3;
            }
    }
}

static inline size_t alignup(size_t v) { return (v + 255) & ~(size_t)255; }

extern "C" void kernel_launch(void* const* d_in, const int* in_sizes, int n_in,
                              void* d_out, int out_size, void* d_ws, size_t ws_size,
                              hipStream_t stream) {
    const float* x = (const float*)d_in[0];
    const int* edge_src = (const int*)d_in[1];
    const int* edge_dst = (const int*)d_in[2];
    const int* pos_src = (const int*)d_in[3];
    const int* pos_dst = (const int*)d_in[4];
    const int* neg_src = (const int*)d_in[5];
    const int* neg_dst = (const int*)d_in[6];
    const float* Ws1 = (const float*)d_in[7];
    const float* Wn1 = (const float*)d_in[8];
    const float* b1 = (const float*)d_in[9];
    const float* Ws2 = (const float*)d_in[10];
    const float* Wn2 = (const float*)d_in[11];
    const float* b2 = (const float*)d_in[12];
    const float* Wd1 = (const float*)d_in[13];
    const float* bd1 = (const float*)d_in[14];
    const float* Wd2 = (const float*)d_in[15];
    const float* bd2 = (const float*)d_in[16];
    const float* Wd3 = (const float*)d_in[17];
    const float* bd3 = (const float*)d_in[18];
    float* out = (float*)d_out;

    char* p = (char*)d_ws;
    int* deg = (int*)p;            p += alignup(N_NODES * 4);
    int* row_ptr = (int*)p;        p += alignup((N_NODES + 1) * 4);
    int* cursor = (int*)p;         p += alignup(N_NODES * 4);
    int* bsum = (int*)p;           p += alignup(64 * 4);
    int* colA = (int*)p;           p += alignup(N_EDGES * 4);
    unsigned short* A1 = (unsigned short*)p;  p += alignup((size_t)N_NODES * 256 * 2);
    unsigned short* A2 = (unsigned short*)p;  p += alignup((size_t)N_NODES * 256 * 2);
    unsigned short* h2b = (unsigned short*)p; p += alignup((size_t)N_NODES * 128 * 2);
    unsigned short* WT1 = (unsigned short*)p;  p += alignup(32768 * 2);
    unsigned short* WT2 = (unsigned short*)p;  p += alignup(32768 * 2);
    unsigned short* WdT1 = (unsigned short*)p; p += alignup(16384 * 2);
    unsigned short* WdT2 = (unsigned short*)p; p += alignup(16384 * 2);

    hipMemsetAsync(deg, 0, N_NODES * 4, stream);

    k_convert_x<<<(N_NODES * 32 + 255) / 256, 256, 0, stream>>>(x, A1);
    k_prep_w<<<384, 256, 0, stream>>>(Ws1, Wn1, Ws2, Wn2, Wd1, Wd2, WT1, WT2, WdT1, WdT2);

    k_deg<<<(N_EDGES + 255) / 256, 256, 0, stream>>>(edge_dst, deg);
    int nb1 = (N_NODES + 1023) / 1024;
    k_scan1<<<nb1, 1024, 0, stream>>>(deg, row_ptr, bsum, N_NODES);
    k_scan2<<<1, 1, 0, stream>>>(bsum, nb1);
    k_add<<<nb1, 1024, 0, stream>>>(row_ptr, cursor, bsum, N_NODES);
    k_scatter<<<(N_EDGES + 255) / 256, 256, 0, stream>>>(edge_src, edge_dst, cursor, colA);

    // layer 1 (2 nodes per wave -> 8 waves per 256-thread block)
    int nagg = (N_NODES + 7) / 8;   // blocks of 256 threads = 4 waves = 8 nodes
    k_agg<false><<<nagg, 256, 0, stream>>>(x, nullptr, 0, row_ptr, colA, A1 + 128, 256);
    k_gemm<<<(N_NODES + 127) / 128, 256, 0, stream>>>(A1, 256, 256, WT1, b1, A2, 256, N_NODES, 1);

    // layer 2
    k_agg<true><<<nagg, 256, 0, stream>>>(nullptr, A2, 256, row_ptr, colA, A2 + 128, 256);
    k_gemm<<<(N_NODES + 127) / 128, 256, 0, stream>>>(A2, 256, 256, WT2, b2, h2b, 128, N_NODES, 0);

    // decoder: fused gather + MLP, 64 pairs per 128-thread block
    k_mlp<<<(N_PAIRS * 2 + 63) / 64, 128, 0, stream>>>(h2b, pos_src, pos_dst, neg_src, neg_dst,
                                                       WdT1, WdT2, bd1, bd2, Wd3, bd3,
                                                       out, N_PAIRS * 2);
}

// Round 7
// 351.393 us; speedup vs baseline: 1.2926x; 1.0332x over previous
//
#include <hip/hip_runtime.h>
#include <hip/hip_bf16.h>

#define N_NODES 50000
#define N_EDGES 600000
#define N_PAIRS 100000

typedef __attribute__((ext_vector_type(8))) short bf16x8;
typedef __attribute__((ext_vector_type(4))) float f32x4;

__device__ inline unsigned short f2b(float f) {
    unsigned u = __float_as_uint(f);
    unsigned r = u + 0x7fff + ((u >> 16) & 1);
    return (unsigned short)(r >> 16);
}
__device__ inline float b2f(unsigned short h) {
    return __uint_as_float(((unsigned)h) << 16);
}

// ---- convert x (fp32 [N][128]) into A1[:, 0:128] bf16 (ld 256) AND compact xb16 [N][128] ----
__global__ void k_convert_x(const float* __restrict__ x, unsigned short* __restrict__ A1,
                            unsigned short* __restrict__ xb16) {
    int idx = blockIdx.x * blockDim.x + threadIdx.x;
    if (idx >= N_NODES * 32) return;
    int row = idx >> 5, c4 = (idx & 31) * 4;
    float4 v = *(const float4*)(x + row * 128 + c4);
    unsigned lo = (unsigned)f2b(v.x) | ((unsigned)f2b(v.y) << 16);
    unsigned hi = (unsigned)f2b(v.z) | ((unsigned)f2b(v.w) << 16);
    uint2 o; o.x = lo; o.y = hi;
    *(uint2*)(A1 + row * 256 + c4) = o;
    *(uint2*)(xb16 + row * 128 + c4) = o;
}

// ---- build transposed bf16 weights ----
__global__ void k_prep_w(const float* __restrict__ Ws1, const float* __restrict__ Wn1,
                         const float* __restrict__ Ws2, const float* __restrict__ Wn2,
                         const float* __restrict__ Wd1, const float* __restrict__ Wd2,
                         unsigned short* __restrict__ WT1, unsigned short* __restrict__ WT2,
                         unsigned short* __restrict__ WdT1, unsigned short* __restrict__ WdT2) {
    int id = blockIdx.x * blockDim.x + threadIdx.x;
    if (id < 32768) {
        int k = id & 255, n = id >> 8;
        float v = (k < 128) ? Ws1[k * 128 + n] : Wn1[(k - 128) * 128 + n];
        WT1[n * 256 + k] = f2b(v);
    } else if (id < 65536) {
        int r = id - 32768; int k = r & 255, n = r >> 8;
        float v = (k < 128) ? Ws2[k * 128 + n] : Wn2[(k - 128) * 128 + n];
        WT2[n * 256 + k] = f2b(v);
    } else if (id < 81920) {
        int r = id - 65536; int k = r & 127, n = r >> 7;
        WdT1[n * 128 + k] = f2b(Wd1[k * 128 + n]);
    } else if (id < 98304) {
        int r = id - 81920; int k = r & 127, n = r >> 7;
        WdT2[n * 128 + k] = f2b(Wd2[k * 128 + n]);
    }
}

// ---- CSR build ----
__global__ void k_deg(const int* __restrict__ dst, int* __restrict__ deg) {
    int e = blockIdx.x * blockDim.x + threadIdx.x;
    if (e < N_EDGES) atomicAdd(&deg[dst[e]], 1);
}

__global__ void k_scan1(const int* __restrict__ deg, int* __restrict__ row_ptr,
                        int* __restrict__ bsum, int n) {
    __shared__ int tmp[1024];
    int i = blockIdx.x * 1024 + threadIdx.x;
    int d = (i < n) ? deg[i] : 0;
    tmp[threadIdx.x] = d;
    __syncthreads();
    int run = d;
    for (int off = 1; off < 1024; off <<= 1) {
        int t = (threadIdx.x >= off) ? tmp[threadIdx.x - off] : 0;
        __syncthreads();
        run += t;
        tmp[threadIdx.x] = run;
        __syncthreads();
    }
    if (i < n) row_ptr[i] = run - d;
    if (threadIdx.x == 1023) bsum[blockIdx.x] = run;
}

__global__ void k_scan2(int* __restrict__ bsum, int nb) {
    if (blockIdx.x == 0 && threadIdx.x == 0) {
        int acc = 0;
        for (int b = 0; b < nb; b++) { int t = bsum[b]; bsum[b] = acc; acc += t; }
    }
}

__global__ void k_add(int* __restrict__ row_ptr, int* __restrict__ cursor,
                      const int* __restrict__ bsum, int n) {
    int i = blockIdx.x * 1024 + threadIdx.x;
    if (i < n) {
        int v = row_ptr[i] + bsum[blockIdx.x];
        row_ptr[i] = v;
        cursor[i] = v;
    }
    if (i == 0) row_ptr[n] = N_EDGES;
}

__global__ void k_scatter(const int* __restrict__ src, const int* __restrict__ dst,
                          int* __restrict__ cursor, int* __restrict__ colA) {
    int e = blockIdx.x * blockDim.x + threadIdx.x;
    if (e < N_EDGES) {
        int d = dst[e];
        int slot = atomicAdd(&cursor[d], 1);
        colA[slot] = src[e];
    }
}

// ---- mean aggregation v4 (bf16 input): 4 nodes per wave (16 lanes x 16B each),
// chunk=16 edges with all loads hoisted (clamped indices, predicated adds).
// Per-feature association unchanged: pairwise (e0+e1),(e2+e3),... in edge order.
__global__ __launch_bounds__(256) void k_agg(const unsigned short* __restrict__ hb, int ldh,
                                             const int* __restrict__ row_ptr,
                                             const int* __restrict__ colA,
                                             unsigned short* __restrict__ outm, int ldo) {
    int wave = (blockIdx.x * blockDim.x + threadIdx.x) >> 6;
    int lane = threadIdx.x & 63;
    int q = lane >> 4, ql = lane & 15;
    int w = wave * 4 + q;              // N_NODES divisible by 4; grid exact
    if (w >= N_NODES) w = N_NODES - 1; // safety (not hit with exact grid)
    int s = row_ptr[w], e = row_ptr[w + 1];
    float a[8];
#pragma unroll
    for (int j = 0; j < 8; j++) a[j] = 0.f;
    for (int base = s; base < e; base += 16) {
        int ce = (base + ql < e) ? colA[base + ql] : 0;
        int cnt = min(16, e - base);
        int ei[16];
#pragma unroll
        for (int j = 0; j < 16; j++) {
            int sl = (j < cnt) ? j : (cnt - 1);
            ei[j] = __shfl(ce, (q << 4) + sl, 64);
        }
        uint4 v[16];
#pragma unroll
        for (int j = 0; j < 16; j++)
            v[j] = *(const uint4*)(hb + (size_t)ei[j] * ldh + ql * 8);
#pragma unroll
        for (int j = 0; j < 16; j += 2) {
            const unsigned* p0 = (const unsigned*)&v[j];
            const unsigned* p1 = (const unsigned*)&v[j + 1];
            if (j + 1 < cnt) {
#pragma unroll
                for (int t = 0; t < 4; t++) {
                    a[2 * t] += b2f(p0[t] & 0xffff) + b2f(p1[t] & 0xffff);
                    a[2 * t + 1] += b2f(p0[t] >> 16) + b2f(p1[t] >> 16);
                }
            } else if (j < cnt) {
#pragma unroll
                for (int t = 0; t < 4; t++) {
                    a[2 * t] += b2f(p0[t] & 0xffff);
                    a[2 * t + 1] += b2f(p0[t] >> 16);
                }
            }
        }
    }
    float rd = 1.0f / (float)max(e - s, 1);
    uint4 o;
    unsigned* op = (unsigned*)&o;
#pragma unroll
    for (int t = 0; t < 4; t++)
        op[t] = (unsigned)f2b(a[2 * t] * rd) | ((unsigned)f2b(a[2 * t + 1] * rd) << 16);
    *(uint4*)(outm + (size_t)w * ldo + ql * 8) = o;
}

// ---- SAGE layer GEMM: 32 rows/wave, weight frags grouped 8-in-flight ----
__global__ __launch_bounds__(256) void k_gemm(const unsigned short* __restrict__ A, int lda, int K,
                                              const unsigned short* __restrict__ BT,
                                              const float* __restrict__ bias,
                                              unsigned short* __restrict__ Hout, int ldo,
                                              int M, int relu) {
    int wv = threadIdx.x >> 6, lane = threadIdx.x & 63;
    int lr = lane & 15, lq = lane >> 4;
    int r0 = blockIdx.x * 128 + wv * 32;
    int arow0 = min(r0 + lr, M - 1);
    int arow1 = min(r0 + 16 + lr, M - 1);
    f32x4 acc[2][8];
    f32x4 zero = {0.f, 0.f, 0.f, 0.f};
#pragma unroll
    for (int m = 0; m < 2; m++)
#pragma unroll
        for (int ct = 0; ct < 8; ct++) acc[m][ct] = zero;
    for (int kb = 0; kb < K; kb += 32) {
        int ka = kb + lq * 8;
        bf16x8 wf[8];
#pragma unroll
        for (int ct = 0; ct < 8; ct++)
            wf[ct] = *(const bf16x8*)(BT + (ct * 16 + lr) * K + ka);
        bf16x8 af0 = *(const bf16x8*)(A + (size_t)arow0 * lda + ka);
        bf16x8 af1 = *(const bf16x8*)(A + (size_t)arow1 * lda + ka);
#pragma unroll
        for (int ct = 0; ct < 8; ct++) {
            acc[0][ct] = __builtin_amdgcn_mfma_f32_16x16x32_bf16(af0, wf[ct], acc[0][ct], 0, 0, 0);
            acc[1][ct] = __builtin_amdgcn_mfma_f32_16x16x32_bf16(af1, wf[ct], acc[1][ct], 0, 0, 0);
        }
    }
#pragma unroll
    for (int m = 0; m < 2; m++) {
#pragma unroll
        for (int ct = 0; ct < 8; ct++) {
            int colc = ct * 16 + lr;
            float bv = bias[colc];
#pragma unroll
            for (int r = 0; r < 4; r++) {
                int row = r0 + m * 16 + lq * 4 + r;
                if (row < M) {
                    float v = acc[m][ct][r] + bv;
                    if (relu) v = fmaxf(v, 0.f);
                    Hout[(size_t)row * ldo + colc] = f2b(v);
                }
            }
        }
    }
}

// ---- decoder MLP: 128-thread blocks (2 waves), fused register gather ----
__global__ __launch_bounds__(128) void k_mlp(const unsigned short* __restrict__ h2b,
                                             const int* __restrict__ pos_src,
                                             const int* __restrict__ pos_dst,
                                             const int* __restrict__ neg_src,
                                             const int* __restrict__ neg_dst,
                                             const unsigned short* __restrict__ WdT1,
                                             const unsigned short* __restrict__ WdT2,
                                             const float* __restrict__ bd1,
                                             const float* __restrict__ bd2,
                                             const float* __restrict__ Wd3,
                                             const float* __restrict__ bd3,
                                             float* __restrict__ out, int P2) {
    __shared__ unsigned short t1[2][32][136];   // 17,408 B
    const int tid = threadIdx.x;
    const int wv = tid >> 6, lane = tid & 63, lr = lane & 15, lq = lane >> 4;
    const int row0 = blockIdx.x * 64 + wv * 32;
    int p0 = min(row0 + lr, P2 - 1);
    int p1 = min(row0 + 16 + lr, P2 - 1);
    int s0i = (p0 < N_PAIRS) ? pos_src[p0] : neg_src[p0 - N_PAIRS];
    int d0i = (p0 < N_PAIRS) ? pos_dst[p0] : neg_dst[p0 - N_PAIRS];
    int s1i = (p1 < N_PAIRS) ? pos_src[p1] : neg_src[p1 - N_PAIRS];
    int d1i = (p1 < N_PAIRS) ? pos_dst[p1] : neg_dst[p1 - N_PAIRS];
    uint4 za0[4], zb0[4], za1[4], zb1[4];
#pragma unroll
    for (int kb = 0; kb < 4; kb++) {
        int ka = kb * 32 + lq * 8;
        za0[kb] = *(const uint4*)(h2b + (size_t)s0i * 128 + ka);
        zb0[kb] = *(const uint4*)(h2b + (size_t)d0i * 128 + ka);
        za1[kb] = *(const uint4*)(h2b + (size_t)s1i * 128 + ka);
        zb1[kb] = *(const uint4*)(h2b + (size_t)d1i * 128 + ka);
    }
    bf16x8 af0[4], af1[4];
#pragma unroll
    for (int kb = 0; kb < 4; kb++) {
        unsigned r0v[4], r1v[4];
        const unsigned* a0p = (const unsigned*)&za0[kb];
        const unsigned* b0p = (const unsigned*)&zb0[kb];
        const unsigned* a1p = (const unsigned*)&za1[kb];
        const unsigned* b1p = (const unsigned*)&zb1[kb];
#pragma unroll
        for (int j = 0; j < 4; j++) {
            unsigned short lo0 = f2b(b2f(a0p[j] & 0xffff) * b2f(b0p[j] & 0xffff));
            unsigned short hi0 = f2b(b2f(a0p[j] >> 16) * b2f(b0p[j] >> 16));
            r0v[j] = (unsigned)lo0 | ((unsigned)hi0 << 16);
            unsigned short lo1 = f2b(b2f(a1p[j] & 0xffff) * b2f(b1p[j] & 0xffff));
            unsigned short hi1 = f2b(b2f(a1p[j] >> 16) * b2f(b1p[j] >> 16));
            r1v[j] = (unsigned)lo1 | ((unsigned)hi1 << 16);
        }
        af0[kb] = *(const bf16x8*)r0v;
        af1[kb] = *(const bf16x8*)r1v;
    }
    f32x4 zero = {0.f, 0.f, 0.f, 0.f};
    f32x4 acc[2][8];
#pragma unroll
    for (int m = 0; m < 2; m++)
#pragma unroll
        for (int ct = 0; ct < 8; ct++) acc[m][ct] = zero;
#pragma unroll
    for (int kb = 0; kb < 4; kb++) {
        int ka = kb * 32 + lq * 8;
        bf16x8 wf[8];
#pragma unroll
        for (int ct = 0; ct < 8; ct++)
            wf[ct] = *(const bf16x8*)(WdT1 + (ct * 16 + lr) * 128 + ka);
#pragma unroll
        for (int ct = 0; ct < 8; ct++) {
            acc[0][ct] = __builtin_amdgcn_mfma_f32_16x16x32_bf16(af0[kb], wf[ct], acc[0][ct], 0, 0, 0);
            acc[1][ct] = __builtin_amdgcn_mfma_f32_16x16x32_bf16(af1[kb], wf[ct], acc[1][ct], 0, 0, 0);
        }
    }
#pragma unroll
    for (int m = 0; m < 2; m++)
#pragma unroll
        for (int ct = 0; ct < 8; ct++) {
            int colc = ct * 16 + lr;
            float bv = bd1[colc];
#pragma unroll
            for (int r = 0; r < 4; r++) {
                float v = fmaxf(acc[m][ct][r] + bv, 0.f);
                t1[wv][m * 16 + lq * 4 + r][colc] = f2b(v);
            }
        }
    __syncthreads();
#pragma unroll
    for (int m = 0; m < 2; m++)
#pragma unroll
        for (int ct = 0; ct < 8; ct++) acc[m][ct] = zero;
#pragma unroll
    for (int kb = 0; kb < 4; kb++) {
        int ka = kb * 32 + lq * 8;
        bf16x8 wf[8];
#pragma unroll
        for (int ct = 0; ct < 8; ct++)
            wf[ct] = *(const bf16x8*)(WdT2 + (ct * 16 + lr) * 128 + ka);
        bf16x8 bf0 = *(const bf16x8*)(&t1[wv][lr][ka]);
        bf16x8 bf1 = *(const bf16x8*)(&t1[wv][16 + lr][ka]);
#pragma unroll
        for (int ct = 0; ct < 8; ct++) {
            acc[0][ct] = __builtin_amdgcn_mfma_f32_16x16x32_bf16(bf0, wf[ct], acc[0][ct], 0, 0, 0);
            acc[1][ct] = __builtin_amdgcn_mfma_f32_16x16x32_bf16(bf1, wf[ct], acc[1][ct], 0, 0, 0);
        }
    }
    float sc[2][4] = {{0.f, 0.f, 0.f, 0.f}, {0.f, 0.f, 0.f, 0.f}};
#pragma unroll
    for (int ct = 0; ct < 8; ct++) {
        int colc = ct * 16 + lr;
        float bv = bd2[colc];
        float w3 = Wd3[colc];
#pragma unroll
        for (int m = 0; m < 2; m++)
#pragma unroll
            for (int r = 0; r < 4; r++) {
                float v = fmaxf(acc[m][ct][r] + bv, 0.f);
                sc[m][r] += v * w3;
            }
    }
#pragma unroll
    for (int mm = 1; mm < 16; mm <<= 1)
#pragma unroll
        for (int m = 0; m < 2; m++)
#pragma unroll
            for (int r = 0; r < 4; r++) sc[m][r] += __shfl_xor(sc[m][r], mm, 64);
    if (lr == 0) {
        float b3 = bd3[0];
#pragma unroll
        for (int m = 0; m < 2; m++)
#pragma unroll
            for (int r = 0; r < 4; r++) {
                int g = row0 + m * 16 + lq * 4 + r;
                if (g < P2) out[g] = sc[m][r] + b3;
            }
    }
}

static inline size_t alignup(size_t v) { return (v + 255) & ~(size_t)255; }

extern "C" void kernel_launch(void* const* d_in, const int* in_sizes, int n_in,
                              void* d_out, int out_size, void* d_ws, size_t ws_size,
                              hipStream_t stream) {
    const float* x = (const float*)d_in[0];
    const int* edge_src = (const int*)d_in[1];
    const int* edge_dst = (const int*)d_in[2];
    const int* pos_src = (const int*)d_in[3];
    const int* pos_dst = (const int*)d_in[4];
    const int* neg_src = (const int*)d_in[5];
    const int* neg_dst = (const int*)d_in[6];
    const float* Ws1 = (const float*)d_in[7];
    const float* Wn1 = (const float*)d_in[8];
    const float* b1 = (const float*)d_in[9];
    const float* Ws2 = (const float*)d_in[10];
    const float* Wn2 = (const float*)d_in[11];
    const float* b2 = (const float*)d_in[12];
    const float* Wd1 = (const float*)d_in[13];
    const float* bd1 = (const float*)d_in[14];
    const float* Wd2 = (const float*)d_in[15];
    const float* bd2 = (const float*)d_in[16];
    const float* Wd3 = (const float*)d_in[17];
    const float* bd3 = (const float*)d_in[18];
    float* out = (float*)d_out;

    char* p = (char*)d_ws;
    int* deg = (int*)p;            p += alignup(N_NODES * 4);
    int* row_ptr = (int*)p;        p += alignup((N_NODES + 1) * 4);
    int* cursor = (int*)p;         p += alignup(N_NODES * 4);
    int* bsum = (int*)p;           p += alignup(64 * 4);
    int* colA = (int*)p;           p += alignup(N_EDGES * 4);
    unsigned short* A1 = (unsigned short*)p;  p += alignup((size_t)N_NODES * 256 * 2);
    unsigned short* A2 = (unsigned short*)p;  p += alignup((size_t)N_NODES * 256 * 2);
    unsigned short* h2b = (unsigned short*)p; p += alignup((size_t)N_NODES * 128 * 2);
    unsigned short* WT1 = (unsigned short*)p;  p += alignup(32768 * 2);
    unsigned short* WT2 = (unsigned short*)p;  p += alignup(32768 * 2);
    unsigned short* WdT1 = (unsigned short*)p; p += alignup(16384 * 2);
    unsigned short* WdT2 = (unsigned short*)p; p += alignup(16384 * 2);
    // compact bf16 copy of x, aliased onto h2b (dead until gemm2 overwrites it,
    // which happens after agg1 has consumed xb16)
    unsigned short* xb16 = h2b;

    hipMemsetAsync(deg, 0, N_NODES * 4, stream);

    k_convert_x<<<(N_NODES * 32 + 255) / 256, 256, 0, stream>>>(x, A1, xb16);
    k_prep_w<<<384, 256, 0, stream>>>(Ws1, Wn1, Ws2, Wn2, Wd1, Wd2, WT1, WT2, WdT1, WdT2);

    k_deg<<<(N_EDGES + 255) / 256, 256, 0, stream>>>(edge_dst, deg);
    int nb1 = (N_NODES + 1023) / 1024;
    k_scan1<<<nb1, 1024, 0, stream>>>(deg, row_ptr, bsum, N_NODES);
    k_scan2<<<1, 1, 0, stream>>>(bsum, nb1);
    k_add<<<nb1, 1024, 0, stream>>>(row_ptr, cursor, bsum, N_NODES);
    k_scatter<<<(N_EDGES + 255) / 256, 256, 0, stream>>>(edge_src, edge_dst, cursor, colA);

    // 4 nodes/wave, 4 waves/block -> 16 nodes/block; 50000/16 -> 3125 blocks
    int nagg = (N_NODES + 15) / 16;

    // layer 1 (bf16 aggregation from compact xb16)
    k_agg<<<nagg, 256, 0, stream>>>(xb16, 128, row_ptr, colA, A1 + 128, 256);
    k_gemm<<<(N_NODES + 127) / 128, 256, 0, stream>>>(A1, 256, 256, WT1, b1, A2, 256, N_NODES, 1);

    // layer 2
    k_agg<<<nagg, 256, 0, stream>>>(A2, 256, row_ptr, colA, A2 + 128, 256);
    k_gemm<<<(N_NODES + 127) / 128, 256, 0, stream>>>(A2, 256, 256, WT2, b2, h2b, 128, N_NODES, 0);

    // decoder: fused gather + MLP
    k_mlp<<<(N_PAIRS * 2 + 63) / 64, 128, 0, stream>>>(h2b, pos_src, pos_dst, neg_src, neg_dst,
                                                       WdT1, WdT2, bd1, bd2, Wd3, bd3,
                                                       out, N_PAIRS * 2);
}

// Round 8
// 333.793 us; speedup vs baseline: 1.3608x; 1.0527x over previous
//
#include <hip/hip_runtime.h>
#include <hip/hip_bf16.h>

#define N_NODES 50000
#define N_EDGES 600000
#define N_PAIRS 100000

typedef __attribute__((ext_vector_type(8))) short bf16x8;
typedef __attribute__((ext_vector_type(4))) float f32x4;

__device__ inline unsigned short f2b(float f) {
    unsigned u = __float_as_uint(f);
    unsigned r = u + 0x7fff + ((u >> 16) & 1);
    return (unsigned short)(r >> 16);
}
__device__ inline float b2f(unsigned short h) {
    return __uint_as_float(((unsigned)h) << 16);
}

// ---- convert x to bf16 (A1 ld256 + compact xb16) AND edge-degree histogram ----
__global__ void k_convert_x(const float* __restrict__ x, unsigned short* __restrict__ A1,
                            unsigned short* __restrict__ xb16,
                            const int* __restrict__ edge_dst, int* __restrict__ deg) {
    int idx = blockIdx.x * blockDim.x + threadIdx.x;
    if (idx < N_EDGES) atomicAdd(&deg[edge_dst[idx]], 1);
    if (idx >= N_NODES * 32) return;
    int row = idx >> 5, c4 = (idx & 31) * 4;
    float4 v = *(const float4*)(x + row * 128 + c4);
    unsigned lo = (unsigned)f2b(v.x) | ((unsigned)f2b(v.y) << 16);
    unsigned hi = (unsigned)f2b(v.z) | ((unsigned)f2b(v.w) << 16);
    uint2 o; o.x = lo; o.y = hi;
    *(uint2*)(A1 + row * 256 + c4) = o;
    *(uint2*)(xb16 + row * 128 + c4) = o;
}

// ---- build transposed bf16 weights ----
__global__ void k_prep_w(const float* __restrict__ Ws1, const float* __restrict__ Wn1,
                         const float* __restrict__ Ws2, const float* __restrict__ Wn2,
                         const float* __restrict__ Wd1, const float* __restrict__ Wd2,
                         unsigned short* __restrict__ WT1, unsigned short* __restrict__ WT2,
                         unsigned short* __restrict__ WdT1, unsigned short* __restrict__ WdT2) {
    int id = blockIdx.x * blockDim.x + threadIdx.x;
    if (id < 32768) {
        int k = id & 255, n = id >> 8;
        float v = (k < 128) ? Ws1[k * 128 + n] : Wn1[(k - 128) * 128 + n];
        WT1[n * 256 + k] = f2b(v);
    } else if (id < 65536) {
        int r = id - 32768; int k = r & 255, n = r >> 8;
        float v = (k < 128) ? Ws2[k * 128 + n] : Wn2[(k - 128) * 128 + n];
        WT2[n * 256 + k] = f2b(v);
    } else if (id < 81920) {
        int r = id - 65536; int k = r & 127, n = r >> 7;
        WdT1[n * 128 + k] = f2b(Wd1[k * 128 + n]);
    } else if (id < 98304) {
        int r = id - 81920; int k = r & 127, n = r >> 7;
        WdT2[n * 128 + k] = f2b(Wd2[k * 128 + n]);
    }
}

// ---- CSR build ----
__global__ void k_scan1(const int* __restrict__ deg, int* __restrict__ row_ptr,
                        int* __restrict__ bsum, int n) {
    __shared__ int tmp[1024];
    int i = blockIdx.x * 1024 + threadIdx.x;
    int d = (i < n) ? deg[i] : 0;
    tmp[threadIdx.x] = d;
    __syncthreads();
    int run = d;
    for (int off = 1; off < 1024; off <<= 1) {
        int t = (threadIdx.x >= off) ? tmp[threadIdx.x - off] : 0;
        __syncthreads();
        run += t;
        tmp[threadIdx.x] = run;
        __syncthreads();
    }
    if (i < n) row_ptr[i] = run - d;       // block-local exclusive
    if (threadIdx.x == 1023) bsum[blockIdx.x] = run;   // block total
}

// fused: global prefix from bsum totals computed per block (<=49 adds)
__global__ void k_add(int* __restrict__ row_ptr, int* __restrict__ cursor,
                      const int* __restrict__ bsum, int n) {
    __shared__ int prefix;
    if (threadIdx.x == 0) {
        int acc = 0;
        for (int j = 0; j < (int)blockIdx.x; j++) acc += bsum[j];
        prefix = acc;
    }
    __syncthreads();
    int i = blockIdx.x * 1024 + threadIdx.x;
    if (i < n) {
        int v = row_ptr[i] + prefix;
        row_ptr[i] = v;
        cursor[i] = v;
    }
    if (i == 0) row_ptr[n] = N_EDGES;
}

__global__ void k_scatter(const int* __restrict__ src, const int* __restrict__ dst,
                          int* __restrict__ cursor, int* __restrict__ colA) {
    int e = blockIdx.x * blockDim.x + threadIdx.x;
    if (e < N_EDGES) {
        int d = dst[e];
        int slot = atomicAdd(&cursor[d], 1);
        colA[slot] = src[e];
    }
}

// ---- mean aggregation (bf16 input): 4 nodes per wave (16 lanes x 16B each),
// chunk=16 edges with all loads hoisted (clamped indices, predicated adds).
__global__ __launch_bounds__(256) void k_agg(const unsigned short* __restrict__ hb, int ldh,
                                             const int* __restrict__ row_ptr,
                                             const int* __restrict__ colA,
                                             unsigned short* __restrict__ outm, int ldo) {
    int wave = (blockIdx.x * blockDim.x + threadIdx.x) >> 6;
    int lane = threadIdx.x & 63;
    int q = lane >> 4, ql = lane & 15;
    int w = wave * 4 + q;
    if (w >= N_NODES) w = N_NODES - 1;
    int s = row_ptr[w], e = row_ptr[w + 1];
    float a[8];
#pragma unroll
    for (int j = 0; j < 8; j++) a[j] = 0.f;
    for (int base = s; base < e; base += 16) {
        int ce = (base + ql < e) ? colA[base + ql] : 0;
        int cnt = min(16, e - base);
        int ei[16];
#pragma unroll
        for (int j = 0; j < 16; j++) {
            int sl = (j < cnt) ? j : (cnt - 1);
            ei[j] = __shfl(ce, (q << 4) + sl, 64);
        }
        uint4 v[16];
#pragma unroll
        for (int j = 0; j < 16; j++)
            v[j] = *(const uint4*)(hb + (size_t)ei[j] * ldh + ql * 8);
#pragma unroll
        for (int j = 0; j < 16; j += 2) {
            const unsigned* p0 = (const unsigned*)&v[j];
            const unsigned* p1 = (const unsigned*)&v[j + 1];
            if (j + 1 < cnt) {
#pragma unroll
                for (int t = 0; t < 4; t++) {
                    a[2 * t] += b2f(p0[t] & 0xffff) + b2f(p1[t] & 0xffff);
                    a[2 * t + 1] += b2f(p0[t] >> 16) + b2f(p1[t] >> 16);
                }
            } else if (j < cnt) {
#pragma unroll
                for (int t = 0; t < 4; t++) {
                    a[2 * t] += b2f(p0[t] & 0xffff);
                    a[2 * t + 1] += b2f(p0[t] >> 16);
                }
            }
        }
    }
    float rd = 1.0f / (float)max(e - s, 1);
    uint4 o;
    unsigned* op = (unsigned*)&o;
#pragma unroll
    for (int t = 0; t < 4; t++)
        op[t] = (unsigned)f2b(a[2 * t] * rd) | ((unsigned)f2b(a[2 * t + 1] * rd) << 16);
    *(uint4*)(outm + (size_t)w * ldo + ql * 8) = o;
}

// ---- SAGE layer GEMM: 32 rows/wave, weight frags grouped 8-in-flight ----
__global__ __launch_bounds__(256) void k_gemm(const unsigned short* __restrict__ A, int lda, int K,
                                              const unsigned short* __restrict__ BT,
                                              const float* __restrict__ bias,
                                              unsigned short* __restrict__ Hout, int ldo,
                                              int M, int relu) {
    int wv = threadIdx.x >> 6, lane = threadIdx.x & 63;
    int lr = lane & 15, lq = lane >> 4;
    int r0 = blockIdx.x * 128 + wv * 32;
    int arow0 = min(r0 + lr, M - 1);
    int arow1 = min(r0 + 16 + lr, M - 1);
    f32x4 acc[2][8];
    f32x4 zero = {0.f, 0.f, 0.f, 0.f};
#pragma unroll
    for (int m = 0; m < 2; m++)
#pragma unroll
        for (int ct = 0; ct < 8; ct++) acc[m][ct] = zero;
    for (int kb = 0; kb < K; kb += 32) {
        int ka = kb + lq * 8;
        bf16x8 wf[8];
#pragma unroll
        for (int ct = 0; ct < 8; ct++)
            wf[ct] = *(const bf16x8*)(BT + (ct * 16 + lr) * K + ka);
        bf16x8 af0 = *(const bf16x8*)(A + (size_t)arow0 * lda + ka);
        bf16x8 af1 = *(const bf16x8*)(A + (size_t)arow1 * lda + ka);
#pragma unroll
        for (int ct = 0; ct < 8; ct++) {
            acc[0][ct] = __builtin_amdgcn_mfma_f32_16x16x32_bf16(af0, wf[ct], acc[0][ct], 0, 0, 0);
            acc[1][ct] = __builtin_amdgcn_mfma_f32_16x16x32_bf16(af1, wf[ct], acc[1][ct], 0, 0, 0);
        }
    }
#pragma unroll
    for (int m = 0; m < 2; m++) {
#pragma unroll
        for (int ct = 0; ct < 8; ct++) {
            int colc = ct * 16 + lr;
            float bv = bias[colc];
#pragma unroll
            for (int r = 0; r < 4; r++) {
                int row = r0 + m * 16 + lq * 4 + r;
                if (row < M) {
                    float v = acc[m][ct][r] + bv;
                    if (relu) v = fmaxf(v, 0.f);
                    Hout[(size_t)row * ldo + colc] = f2b(v);
                }
            }
        }
    }
}

// ---- decoder MLP v5: 64-thread (1-wave) blocks, fused register gather ----
// 1 wave => 8.7KB LDS/block (~16-18 blocks/CU) and __syncthreads degenerates
// to a waitcnt (no inter-wave barrier skew). Math identical to v4.
__global__ __launch_bounds__(64) void k_mlp(const unsigned short* __restrict__ h2b,
                                            const int* __restrict__ pos_src,
                                            const int* __restrict__ pos_dst,
                                            const int* __restrict__ neg_src,
                                            const int* __restrict__ neg_dst,
                                            const unsigned short* __restrict__ WdT1,
                                            const unsigned short* __restrict__ WdT2,
                                            const float* __restrict__ bd1,
                                            const float* __restrict__ bd2,
                                            const float* __restrict__ Wd3,
                                            const float* __restrict__ bd3,
                                            float* __restrict__ out, int P2) {
    __shared__ unsigned short t1[32][136];   // 8,704 B
    const int lane = threadIdx.x & 63, lr = lane & 15, lq = lane >> 4;
    const int row0 = blockIdx.x * 32;
    int p0 = min(row0 + lr, P2 - 1);
    int p1 = min(row0 + 16 + lr, P2 - 1);
    int s0i = (p0 < N_PAIRS) ? pos_src[p0] : neg_src[p0 - N_PAIRS];
    int d0i = (p0 < N_PAIRS) ? pos_dst[p0] : neg_dst[p0 - N_PAIRS];
    int s1i = (p1 < N_PAIRS) ? pos_src[p1] : neg_src[p1 - N_PAIRS];
    int d1i = (p1 < N_PAIRS) ? pos_dst[p1] : neg_dst[p1 - N_PAIRS];
    uint4 za0[4], zb0[4], za1[4], zb1[4];
#pragma unroll
    for (int kb = 0; kb < 4; kb++) {
        int ka = kb * 32 + lq * 8;
        za0[kb] = *(const uint4*)(h2b + (size_t)s0i * 128 + ka);
        zb0[kb] = *(const uint4*)(h2b + (size_t)d0i * 128 + ka);
        za1[kb] = *(const uint4*)(h2b + (size_t)s1i * 128 + ka);
        zb1[kb] = *(const uint4*)(h2b + (size_t)d1i * 128 + ka);
    }
    bf16x8 af0[4], af1[4];
#pragma unroll
    for (int kb = 0; kb < 4; kb++) {
        unsigned r0v[4], r1v[4];
        const unsigned* a0p = (const unsigned*)&za0[kb];
        const unsigned* b0p = (const unsigned*)&zb0[kb];
        const unsigned* a1p = (const unsigned*)&za1[kb];
        const unsigned* b1p = (const unsigned*)&zb1[kb];
#pragma unroll
        for (int j = 0; j < 4; j++) {
            unsigned short lo0 = f2b(b2f(a0p[j] & 0xffff) * b2f(b0p[j] & 0xffff));
            unsigned short hi0 = f2b(b2f(a0p[j] >> 16) * b2f(b0p[j] >> 16));
            r0v[j] = (unsigned)lo0 | ((unsigned)hi0 << 16);
            unsigned short lo1 = f2b(b2f(a1p[j] & 0xffff) * b2f(b1p[j] & 0xffff));
            unsigned short hi1 = f2b(b2f(a1p[j] >> 16) * b2f(b1p[j] >> 16));
            r1v[j] = (unsigned)lo1 | ((unsigned)hi1 << 16);
        }
        af0[kb] = *(const bf16x8*)r0v;
        af1[kb] = *(const bf16x8*)r1v;
    }
    f32x4 zero = {0.f, 0.f, 0.f, 0.f};
    f32x4 acc[2][8];
#pragma unroll
    for (int m = 0; m < 2; m++)
#pragma unroll
        for (int ct = 0; ct < 8; ct++) acc[m][ct] = zero;
#pragma unroll
    for (int kb = 0; kb < 4; kb++) {
        int ka = kb * 32 + lq * 8;
        bf16x8 wf[8];
#pragma unroll
        for (int ct = 0; ct < 8; ct++)
            wf[ct] = *(const bf16x8*)(WdT1 + (ct * 16 + lr) * 128 + ka);
#pragma unroll
        for (int ct = 0; ct < 8; ct++) {
            acc[0][ct] = __builtin_amdgcn_mfma_f32_16x16x32_bf16(af0[kb], wf[ct], acc[0][ct], 0, 0, 0);
            acc[1][ct] = __builtin_amdgcn_mfma_f32_16x16x32_bf16(af1[kb], wf[ct], acc[1][ct], 0, 0, 0);
        }
    }
#pragma unroll
    for (int m = 0; m < 2; m++)
#pragma unroll
        for (int ct = 0; ct < 8; ct++) {
            int colc = ct * 16 + lr;
            float bv = bd1[colc];
#pragma unroll
            for (int r = 0; r < 4; r++) {
                float v = fmaxf(acc[m][ct][r] + bv, 0.f);
                t1[m * 16 + lq * 4 + r][colc] = f2b(v);
            }
        }
    __syncthreads();
#pragma unroll
    for (int m = 0; m < 2; m++)
#pragma unroll
        for (int ct = 0; ct < 8; ct++) acc[m][ct] = zero;
#pragma unroll
    for (int kb = 0; kb < 4; kb++) {
        int ka = kb * 32 + lq * 8;
        bf16x8 wf[8];
#pragma unroll
        for (int ct = 0; ct < 8; ct++)
            wf[ct] = *(const bf16x8*)(WdT2 + (ct * 16 + lr) * 128 + ka);
        bf16x8 bf0 = *(const bf16x8*)(&t1[lr][ka]);
        bf16x8 bf1 = *(const bf16x8*)(&t1[16 + lr][ka]);
#pragma unroll
        for (int ct = 0; ct < 8; ct++) {
            acc[0][ct] = __builtin_amdgcn_mfma_f32_16x16x32_bf16(bf0, wf[ct], acc[0][ct], 0, 0, 0);
            acc[1][ct] = __builtin_amdgcn_mfma_f32_16x16x32_bf16(bf1, wf[ct], acc[1][ct], 0, 0, 0);
        }
    }
    float sc[2][4] = {{0.f, 0.f, 0.f, 0.f}, {0.f, 0.f, 0.f, 0.f}};
#pragma unroll
    for (int ct = 0; ct < 8; ct++) {
        int colc = ct * 16 + lr;
        float bv = bd2[colc];
        float w3 = Wd3[colc];
#pragma unroll
        for (int m = 0; m < 2; m++)
#pragma unroll
            for (int r = 0; r < 4; r++) {
                float v = fmaxf(acc[m][ct][r] + bv, 0.f);
                sc[m][r] += v * w3;
            }
    }
#pragma unroll
    for (int mm = 1; mm < 16; mm <<= 1)
#pragma unroll
        for (int m = 0; m < 2; m++)
#pragma unroll
            for (int r = 0; r < 4; r++) sc[m][r] += __shfl_xor(sc[m][r], mm, 64);
    if (lr == 0) {
        float b3 = bd3[0];
#pragma unroll
        for (int m = 0; m < 2; m++)
#pragma unroll
            for (int r = 0; r < 4; r++) {
                int g = row0 + m * 16 + lq * 4 + r;
                if (g < P2) out[g] = sc[m][r] + b3;
            }
    }
}

static inline size_t alignup(size_t v) { return (v + 255) & ~(size_t)255; }

extern "C" void kernel_launch(void* const* d_in, const int* in_sizes, int n_in,
                              void* d_out, int out_size, void* d_ws, size_t ws_size,
                              hipStream_t stream) {
    const float* x = (const float*)d_in[0];
    const int* edge_src = (const int*)d_in[1];
    const int* edge_dst = (const int*)d_in[2];
    const int* pos_src = (const int*)d_in[3];
    const int* pos_dst = (const int*)d_in[4];
    const int* neg_src = (const int*)d_in[5];
    const int* neg_dst = (const int*)d_in[6];
    const float* Ws1 = (const float*)d_in[7];
    const float* Wn1 = (const float*)d_in[8];
    const float* b1 = (const float*)d_in[9];
    const float* Ws2 = (const float*)d_in[10];
    const float* Wn2 = (const float*)d_in[11];
    const float* b2 = (const float*)d_in[12];
    const float* Wd1 = (const float*)d_in[13];
    const float* bd1 = (const float*)d_in[14];
    const float* Wd2 = (const float*)d_in[15];
    const float* bd2 = (const float*)d_in[16];
    const float* Wd3 = (const float*)d_in[17];
    const float* bd3 = (const float*)d_in[18];
    float* out = (float*)d_out;

    char* p = (char*)d_ws;
    int* deg = (int*)p;            p += alignup(N_NODES * 4);
    int* row_ptr = (int*)p;        p += alignup((N_NODES + 1) * 4);
    int* cursor = (int*)p;         p += alignup(N_NODES * 4);
    int* bsum = (int*)p;           p += alignup(64 * 4);
    int* colA = (int*)p;           p += alignup(N_EDGES * 4);
    unsigned short* A1 = (unsigned short*)p;  p += alignup((size_t)N_NODES * 256 * 2);
    unsigned short* A2 = (unsigned short*)p;  p += alignup((size_t)N_NODES * 256 * 2);
    unsigned short* h2b = (unsigned short*)p; p += alignup((size_t)N_NODES * 128 * 2);
    unsigned short* WT1 = (unsigned short*)p;  p += alignup(32768 * 2);
    unsigned short* WT2 = (unsigned short*)p;  p += alignup(32768 * 2);
    unsigned short* WdT1 = (unsigned short*)p; p += alignup(16384 * 2);
    unsigned short* WdT2 = (unsigned short*)p; p += alignup(16384 * 2);
    // compact bf16 copy of x, aliased onto h2b (consumed by agg1 before gemm2 writes h2b)
    unsigned short* xb16 = h2b;

    hipMemsetAsync(deg, 0, N_NODES * 4, stream);

    k_convert_x<<<(N_NODES * 32 + 255) / 256, 256, 0, stream>>>(x, A1, xb16, edge_dst, deg);
    k_prep_w<<<384, 256, 0, stream>>>(Ws1, Wn1, Ws2, Wn2, Wd1, Wd2, WT1, WT2, WdT1, WdT2);

    int nb1 = (N_NODES + 1023) / 1024;
    k_scan1<<<nb1, 1024, 0, stream>>>(deg, row_ptr, bsum, N_NODES);
    k_add<<<nb1, 1024, 0, stream>>>(row_ptr, cursor, bsum, N_NODES);
    k_scatter<<<(N_EDGES + 255) / 256, 256, 0, stream>>>(edge_src, edge_dst, cursor, colA);

    int nagg = (N_NODES + 15) / 16;

    // layer 1 (bf16 aggregation from compact xb16)
    k_agg<<<nagg, 256, 0, stream>>>(xb16, 128, row_ptr, colA, A1 + 128, 256);
    k_gemm<<<(N_NODES + 127) / 128, 256, 0, stream>>>(A1, 256, 256, WT1, b1, A2, 256, N_NODES, 1);

    // layer 2
    k_agg<<<nagg, 256, 0, stream>>>(A2, 256, row_ptr, colA, A2 + 128, 256);
    k_gemm<<<(N_NODES + 127) / 128, 256, 0, stream>>>(A2, 256, 256, WT2, b2, h2b, 128, N_NODES, 0);

    // decoder: fused gather + MLP, 32 pairs per 1-wave block
    k_mlp<<<(N_PAIRS * 2 + 31) / 32, 64, 0, stream>>>(h2b, pos_src, pos_dst, neg_src, neg_dst,
                                                      WdT1, WdT2, bd1, bd2, Wd3, bd3,
                                                      out, N_PAIRS * 2);
}